// Round 1
// baseline (1140.338 us; speedup 1.0000x reference)
//
#include <hip/hip_runtime.h>
#include <hip/hip_bf16.h>
#include <math.h>

// ---------------- problem constants ----------------
#define NN      8192
#define VV      8
#define PP      1024      // N / V
#define MM      2048
#define HE_DIM  1024
#define ST_DIM  512
#define D_OUT   256
#define K_HG    5
#define RADIUS  150.0f
#define TEMP    0.07f
#define EPSF    1e-12f

// ---------------- row L2 norm reciprocal ----------------
__global__ __launch_bounds__(256) void rownorm_kernel(const float* __restrict__ A,
                                                      float* __restrict__ rn, int K) {
    int row = blockIdx.x;
    const float* a = A + (long)row * K;
    float s = 0.0f;
    for (int j = threadIdx.x; j < K; j += 256) { float x = a[j]; s += x * x; }
    __shared__ float red[256];
    red[threadIdx.x] = s; __syncthreads();
    for (int o = 128; o > 0; o >>= 1) {
        if (threadIdx.x < o) red[threadIdx.x] += red[threadIdx.x + o];
        __syncthreads();
    }
    if (threadIdx.x == 0) rn[row] = 1.0f / fmaxf(sqrtf(red[0]), EPSF);
}

// ---------------- region centroids ----------------
__global__ __launch_bounds__(256) void centers_kernel(const float* __restrict__ T,
                                                      float* __restrict__ centers) {
    int v = blockIdx.x;
    float sx = 0.0f, sy = 0.0f;
    for (int i = threadIdx.x; i < PP; i += 256) {
        sx += T[(long)(v * PP + i) * 2 + 0];
        sy += T[(long)(v * PP + i) * 2 + 1];
    }
    __shared__ float rx[256], ry[256];
    rx[threadIdx.x] = sx; ry[threadIdx.x] = sy; __syncthreads();
    for (int o = 128; o > 0; o >>= 1) {
        if (threadIdx.x < o) { rx[threadIdx.x] += rx[threadIdx.x + o]; ry[threadIdx.x] += ry[threadIdx.x + o]; }
        __syncthreads();
    }
    if (threadIdx.x == 0) {
        centers[v * 2 + 0] = rx[0] / (float)PP;
        centers[v * 2 + 1] = ry[0] / (float)PP;
    }
}

// ---------------- radius mask ----------------
__global__ __launch_bounds__(256) void mask_kernel(const float* __restrict__ centers,
                                                   const float* __restrict__ S,
                                                   int* __restrict__ mask,
                                                   int* __restrict__ maskcnt) {
    int t = blockIdx.x * 256 + threadIdx.x;
    if (t >= VV * MM) return;
    int v = t / MM, m = t - v * MM;
    float dx = centers[v * 2 + 0] - S[m * 2 + 0];
    float dy = centers[v * 2 + 1] - S[m * 2 + 1];
    int in = (sqrtf(dx * dx + dy * dy) < RADIUS) ? 1 : 0;
    mask[t] = in;
    if (in) atomicAdd(&maskcnt[v], 1);
}

// ---------------- generic f32 GEMM  C = A @ B^T  (optional row/col scaling) ----------------
// tiles 64x64, BK=16, 256 threads, 4x4 per thread. All dims divide evenly for our uses.
__global__ __launch_bounds__(256) void gemm_nt_kernel(
    const float* __restrict__ A, const float* __restrict__ B, float* __restrict__ C,
    int M, int Nn, int K,
    long strideAz, long strideBz, long strideCz,
    const float* __restrict__ rnA, const float* __restrict__ rnB, int rnStrideZ)
{
    int z = blockIdx.z;
    A += (long)z * strideAz;
    B += (long)z * strideBz;
    C += (long)z * strideCz;
    const int bm = blockIdx.y * 64;
    const int bn = blockIdx.x * 64;
    __shared__ float As[16][64 + 4];
    __shared__ float Bs[16][64 + 4];
    const int tid = threadIdx.x;
    const int tx = tid & 15, ty = tid >> 4;
    const int lr = tid >> 2;          // 0..63
    const int lk = (tid & 3) * 4;     // 0,4,8,12
    float acc[4][4] = {{0.f}};
    for (int k0 = 0; k0 < K; k0 += 16) {
        float4 av = *reinterpret_cast<const float4*>(A + (long)(bm + lr) * K + k0 + lk);
        float4 bv = *reinterpret_cast<const float4*>(B + (long)(bn + lr) * K + k0 + lk);
        As[lk + 0][lr] = av.x; As[lk + 1][lr] = av.y; As[lk + 2][lr] = av.z; As[lk + 3][lr] = av.w;
        Bs[lk + 0][lr] = bv.x; Bs[lk + 1][lr] = bv.y; Bs[lk + 2][lr] = bv.z; Bs[lk + 3][lr] = bv.w;
        __syncthreads();
        #pragma unroll
        for (int kk = 0; kk < 16; ++kk) {
            float a0 = As[kk][ty * 4 + 0], a1 = As[kk][ty * 4 + 1],
                  a2 = As[kk][ty * 4 + 2], a3 = As[kk][ty * 4 + 3];
            float b0 = Bs[kk][tx * 4 + 0], b1 = Bs[kk][tx * 4 + 1],
                  b2 = Bs[kk][tx * 4 + 2], b3 = Bs[kk][tx * 4 + 3];
            acc[0][0] += a0 * b0; acc[0][1] += a0 * b1; acc[0][2] += a0 * b2; acc[0][3] += a0 * b3;
            acc[1][0] += a1 * b0; acc[1][1] += a1 * b1; acc[1][2] += a1 * b2; acc[1][3] += a1 * b3;
            acc[2][0] += a2 * b0; acc[2][1] += a2 * b1; acc[2][2] += a2 * b2; acc[2][3] += a2 * b3;
            acc[3][0] += a3 * b0; acc[3][1] += a3 * b1; acc[3][2] += a3 * b2; acc[3][3] += a3 * b3;
        }
        __syncthreads();
    }
    #pragma unroll
    for (int i = 0; i < 4; ++i) {
        int row = bm + ty * 4 + i;
        float ra = rnA ? rnA[(long)z * rnStrideZ + row] : 1.0f;
        #pragma unroll
        for (int j = 0; j < 4; ++j) {
            int col = bn + tx * 4 + j;
            float rb = rnB ? rnB[(long)z * rnStrideZ + col] : 1.0f;
            C[(long)row * Nn + col] = acc[i][j] * ra * rb;
        }
    }
}

// ---------------- top-5 per row (one wave per row, optional column mask) ----------------
__global__ __launch_bounds__(64) void topk_kernel(
    const float* __restrict__ sim, long simStrideZ, int n,
    const int* __restrict__ mask, int maskStrideZ,
    int* __restrict__ outIdx, int rowsPerZ)
{
    int gb = blockIdx.x;
    int z = gb / rowsPerZ;
    int e = gb - z * rowsPerZ;
    int lane = threadIdx.x;
    const int* mk = mask ? (mask + (long)z * maskStrideZ) : nullptr;
    if (mk && mk[e] == 0) {
        if (lane == 0) {
            #pragma unroll
            for (int r = 0; r < K_HG; ++r) outIdx[(long)gb * K_HG + r] = -1;
        }
        return;
    }
    const float* row = sim + (long)z * simStrideZ + (long)e * n;
    float v[K_HG]; int ix[K_HG];
    #pragma unroll
    for (int r = 0; r < K_HG; ++r) { v[r] = -INFINITY; ix[r] = 0x7fffffff; }
    for (int j = lane; j < n; j += 64) {
        if (mk && mk[j] == 0) continue;
        float s = row[j];
        if (s > v[K_HG - 1]) {
            int p = K_HG - 1;
            #pragma unroll
            for (int q = K_HG - 1; q >= 1; --q) {
                if (s > v[q - 1]) { v[q] = v[q - 1]; ix[q] = ix[q - 1]; p = q - 1; }
                else break;
            }
            v[p] = s; ix[p] = j;
        }
    }
    // merge 64 sorted-5 lists: 5 rounds of wave argmax (tie -> min index)
    for (int r = 0; r < K_HG; ++r) {
        float bv = v[0]; int bi = ix[0];
        for (int off = 32; off > 0; off >>= 1) {
            float ov = __shfl_xor(bv, off, 64);
            int   oi = __shfl_xor(bi, off, 64);
            if (ov > bv || (ov == bv && oi < bi)) { bv = ov; bi = oi; }
        }
        if (lane == 0) outIdx[(long)gb * K_HG + r] = bi;
        if (v[0] == bv && ix[0] == bi) {
            #pragma unroll
            for (int p = 0; p < K_HG - 1; ++p) { v[p] = v[p + 1]; ix[p] = ix[p + 1]; }
            v[K_HG - 1] = -INFINITY; ix[K_HG - 1] = 0x7fffffff;
        }
    }
}

// ---------------- node degrees dv ----------------
__global__ __launch_bounds__(256) void dv_kernel(const int* __restrict__ idx,
                                                 float* __restrict__ dv,
                                                 int totalEdges, int rowsPerZ) {
    int t = blockIdx.x * 256 + threadIdx.x;
    if (t >= totalEdges * K_HG) return;
    int ge = t / K_HG;
    int z = ge / rowsPerZ;
    int m = idx[t];
    if (m < 0 || m >= rowsPerZ) return;
    atomicAdd(&dv[z * rowsPerZ + m], 1.0f);
}

// ---------------- edge sum (H^T Dv^-1/2 Xw / de) + scatter (H @ ...) ----------------
__global__ __launch_bounds__(256) void edge_kernel(
    const int* __restrict__ idx, const float* __restrict__ Xw,
    const float* __restrict__ dv, float* __restrict__ acc,
    int rowsPerZ, int xwStrideZ)
{
    int ge = blockIdx.x;
    int z = ge / rowsPerZ;
    int d = threadIdx.x;
    int mm[K_HG];
    #pragma unroll
    for (int k = 0; k < K_HG; ++k) mm[k] = idx[(long)ge * K_HG + k];
    if (mm[0] < 0) return;   // unmasked ST edge
    float val = 0.0f;
    #pragma unroll
    for (int k = 0; k < K_HG; ++k) {
        int m = mm[k];
        if (m < 0 || m >= rowsPerZ) continue;
        float w = rsqrtf(fmaxf(dv[z * rowsPerZ + m], EPSF));
        val += w * Xw[(long)(z * xwStrideZ + m) * D_OUT + d];
    }
    val *= (1.0f / (float)K_HG);   // de = 5
    #pragma unroll
    for (int k = 0; k < K_HG; ++k) {
        int m = mm[k];
        if (m < 0 || m >= rowsPerZ) continue;
        atomicAdd(&acc[(long)(z * rowsPerZ + m) * D_OUT + d], val);
    }
}

// ---------------- Dv^-1/2 scale + GELU + pool ----------------
__global__ __launch_bounds__(256) void pool_kernel(
    const float* __restrict__ acc, const float* __restrict__ dv,
    const int* __restrict__ mask, const int* __restrict__ maskcnt,
    float* __restrict__ zout, int rowsPerZ)
{
    int z = blockIdx.x, d = threadIdx.x;
    float s = 0.0f;
    for (int i = 0; i < rowsPerZ; ++i) {
        int g = z * rowsPerZ + i;
        if (mask && mask[g] == 0) continue;
        float w = rsqrtf(fmaxf(dv[g], EPSF));
        float x = w * acc[(long)g * D_OUT + d];
        s += 0.5f * x * (1.0f + erff(x * 0.70710678118654752f));   // exact GELU
    }
    float denom = mask ? (float)maskcnt[z] : (float)rowsPerZ;
    zout[z * D_OUT + d] = s / denom;
}

// ---------------- final contrastive loss ----------------
__global__ __launch_bounds__(64) void final_kernel(const float* __restrict__ zhe,
                                                   const float* __restrict__ zst,
                                                   float* __restrict__ out) {
    __shared__ float he[VV][D_OUT];
    __shared__ float st[VV][D_OUT];
    __shared__ float lg[VV][VV];
    __shared__ float rn_he[VV], rn_st[VV];
    int t = threadIdx.x;
    for (int i = t; i < VV * D_OUT; i += 64) {
        he[i >> 8][i & 255] = zhe[i];
        st[i >> 8][i & 255] = zst[i];
    }
    __syncthreads();
    if (t < VV) {
        float s = 0.0f;
        for (int d2 = 0; d2 < D_OUT; ++d2) s += he[t][d2] * he[t][d2];
        rn_he[t] = 1.0f / fmaxf(sqrtf(s), EPSF);
    } else if (t < 2 * VV) {
        int v = t - VV; float s = 0.0f;
        for (int d2 = 0; d2 < D_OUT; ++d2) s += st[v][d2] * st[v][d2];
        rn_st[v] = 1.0f / fmaxf(sqrtf(s), EPSF);
    }
    __syncthreads();
    int v = t >> 3, w2 = t & 7;
    float dot = 0.0f;
    for (int d2 = 0; d2 < D_OUT; ++d2) dot += he[v][d2] * st[w2][d2];
    lg[v][w2] = dot * rn_he[v] * rn_st[w2] / TEMP;
    __syncthreads();
    if (t == 0) {
        float l1 = 0.0f, l2 = 0.0f;
        for (int i = 0; i < VV; ++i) {
            float mx = -1e30f;
            for (int j = 0; j < VV; ++j) mx = fmaxf(mx, lg[i][j]);
            float se = 0.0f;
            for (int j = 0; j < VV; ++j) se += expf(lg[i][j] - mx);
            l1 += lg[i][i] - (mx + logf(se));
            float mx2 = -1e30f;
            for (int j = 0; j < VV; ++j) mx2 = fmaxf(mx2, lg[j][i]);
            float se2 = 0.0f;
            for (int j = 0; j < VV; ++j) se2 += expf(lg[j][i] - mx2);
            l2 += lg[i][i] - (mx2 + logf(se2));
        }
        out[0] = 0.5f * (-(l1 / (float)VV) - (l2 / (float)VV));
    }
}

// ---------------- launch ----------------
extern "C" void kernel_launch(void* const* d_in, const int* in_sizes, int n_in,
                              void* d_out, int out_size, void* d_ws, size_t ws_size,
                              hipStream_t stream) {
    const float* F    = (const float*)d_in[0];
    const float* T    = (const float*)d_in[1];
    // d_in[2]: region_indices (int32) — regions are contiguous equal blocks; unused
    const float* E    = (const float*)d_in[3];
    const float* S    = (const float*)d_in[4];
    const float* W_he = (const float*)d_in[5];
    const float* W_st = (const float*)d_in[6];
    float* out = (float*)d_out;

    size_t off = 0;
    auto take = [&](size_t bytes) -> void* {
        void* p = (char*)d_ws + off;
        off += (bytes + 255) & ~(size_t)255;
        return p;
    };
    float* Xw_he   = (float*)take((size_t)NN * D_OUT * 4);        // 8 MB
    float* Xw_st   = (float*)take((size_t)MM * D_OUT * 4);        // 2 MB
    float* rnF     = (float*)take((size_t)NN * 4);
    float* rnE     = (float*)take((size_t)MM * 4);
    float* centers = (float*)take((size_t)VV * 2 * 4);
    int*   mask    = (int*)  take((size_t)VV * MM * 4);
    int*   maskcnt = (int*)  take((size_t)VV * 4);
    float* he_sim  = (float*)take((size_t)VV * PP * PP * 4);      // 32 MB
    float* st_sim  = (float*)take((size_t)MM * MM * 4);           // 16 MB
    int*   he_idx  = (int*)  take((size_t)NN * K_HG * 4);
    int*   st_idx  = (int*)  take((size_t)VV * MM * K_HG * 4);
    float* he_dv   = (float*)take((size_t)NN * 4);
    float* st_dv   = (float*)take((size_t)VV * MM * 4);
    float* he_acc  = (float*)take((size_t)NN * D_OUT * 4);        // 8 MB
    float* st_acc  = (float*)take((size_t)VV * MM * D_OUT * 4);   // 16 MB
    float* z_he    = (float*)take((size_t)VV * D_OUT * 4);
    float* z_st    = (float*)take((size_t)VV * D_OUT * 4);

    // norms + geometry
    rownorm_kernel<<<NN, 256, 0, stream>>>(F, rnF, HE_DIM);
    rownorm_kernel<<<MM, 256, 0, stream>>>(E, rnE, ST_DIM);
    centers_kernel<<<VV, 256, 0, stream>>>(T, centers);
    hipMemsetAsync(maskcnt, 0, VV * 4, stream);
    mask_kernel<<<(VV * MM + 255) / 256, 256, 0, stream>>>(centers, S, mask, maskcnt);

    // projections Xw = X @ W^T
    {
        dim3 g(D_OUT / 64, NN / 64, 1);
        gemm_nt_kernel<<<g, 256, 0, stream>>>(F, W_he, Xw_he, NN, D_OUT, HE_DIM,
                                              0, 0, 0, nullptr, nullptr, 0);
    }
    {
        dim3 g(D_OUT / 64, MM / 64, 1);
        gemm_nt_kernel<<<g, 256, 0, stream>>>(E, W_st, Xw_st, MM, D_OUT, ST_DIM,
                                              0, 0, 0, nullptr, nullptr, 0);
    }
    // scaled Grams (cosine sims)
    {
        dim3 g(PP / 64, PP / 64, VV);
        gemm_nt_kernel<<<g, 256, 0, stream>>>(F, F, he_sim, PP, PP, HE_DIM,
                                              (long)PP * HE_DIM, (long)PP * HE_DIM,
                                              (long)PP * PP, rnF, rnF, PP);
    }
    {
        dim3 g(MM / 64, MM / 64, 1);
        gemm_nt_kernel<<<g, 256, 0, stream>>>(E, E, st_sim, MM, MM, ST_DIM,
                                              0, 0, 0, rnE, rnE, 0);
    }
    // top-5
    topk_kernel<<<NN, 64, 0, stream>>>(he_sim, (long)PP * PP, PP, nullptr, 0, he_idx, PP);
    topk_kernel<<<VV * MM, 64, 0, stream>>>(st_sim, 0, MM, mask, MM, st_idx, MM);

    // degrees
    hipMemsetAsync(he_dv, 0, (size_t)NN * 4, stream);
    hipMemsetAsync(st_dv, 0, (size_t)VV * MM * 4, stream);
    dv_kernel<<<(NN * K_HG + 255) / 256, 256, 0, stream>>>(he_idx, he_dv, NN, PP);
    dv_kernel<<<(VV * MM * K_HG + 255) / 256, 256, 0, stream>>>(st_idx, st_dv, VV * MM, MM);

    // conv: edge sums + scatter
    hipMemsetAsync(he_acc, 0, (size_t)NN * D_OUT * 4, stream);
    hipMemsetAsync(st_acc, 0, (size_t)VV * MM * D_OUT * 4, stream);
    edge_kernel<<<NN, 256, 0, stream>>>(he_idx, Xw_he, he_dv, he_acc, PP, PP);
    edge_kernel<<<VV * MM, 256, 0, stream>>>(st_idx, Xw_st, st_dv, st_acc, MM, 0);

    // gelu + pool
    pool_kernel<<<VV, 256, 0, stream>>>(he_acc, he_dv, nullptr, nullptr, z_he, PP);
    pool_kernel<<<VV, 256, 0, stream>>>(st_acc, st_dv, mask, maskcnt, z_st, MM);

    // loss
    final_kernel<<<1, 64, 0, stream>>>(z_he, z_st, out);
}

// Round 2
// 648.746 us; speedup vs baseline: 1.7578x; 1.7578x over previous
//
#include <hip/hip_runtime.h>
#include <hip/hip_bf16.h>
#include <math.h>

// ---------------- problem constants ----------------
#define NN      8192
#define VV      8
#define PP      1024      // N / V
#define MM      2048
#define HE_DIM  1024
#define ST_DIM  512
#define D_OUT   256
#define K_HG    5
#define RADIUS  150.0f
#define TEMP    0.07f
#define EPSF    1e-12f

#define POOL_CHUNK 16

// ---------------- row L2 norm reciprocal ----------------
__global__ __launch_bounds__(256) void rownorm_kernel(const float* __restrict__ A,
                                                      float* __restrict__ rn, int K) {
    int row = blockIdx.x;
    const float* a = A + (long)row * K;
    float s = 0.0f;
    for (int j = threadIdx.x; j < K; j += 256) { float x = a[j]; s += x * x; }
    __shared__ float red[256];
    red[threadIdx.x] = s; __syncthreads();
    for (int o = 128; o > 0; o >>= 1) {
        if (threadIdx.x < o) red[threadIdx.x] += red[threadIdx.x + o];
        __syncthreads();
    }
    if (threadIdx.x == 0) rn[row] = 1.0f / fmaxf(sqrtf(red[0]), EPSF);
}

// ---------------- region centroids ----------------
__global__ __launch_bounds__(256) void centers_kernel(const float* __restrict__ T,
                                                      float* __restrict__ centers) {
    int v = blockIdx.x;
    float sx = 0.0f, sy = 0.0f;
    for (int i = threadIdx.x; i < PP; i += 256) {
        sx += T[(long)(v * PP + i) * 2 + 0];
        sy += T[(long)(v * PP + i) * 2 + 1];
    }
    __shared__ float rx[256], ry[256];
    rx[threadIdx.x] = sx; ry[threadIdx.x] = sy; __syncthreads();
    for (int o = 128; o > 0; o >>= 1) {
        if (threadIdx.x < o) { rx[threadIdx.x] += rx[threadIdx.x + o]; ry[threadIdx.x] += ry[threadIdx.x + o]; }
        __syncthreads();
    }
    if (threadIdx.x == 0) {
        centers[v * 2 + 0] = rx[0] / (float)PP;
        centers[v * 2 + 1] = ry[0] / (float)PP;
    }
}

// ---------------- radius mask ----------------
__global__ __launch_bounds__(256) void mask_kernel(const float* __restrict__ centers,
                                                   const float* __restrict__ S,
                                                   int* __restrict__ mask,
                                                   int* __restrict__ maskcnt) {
    int t = blockIdx.x * 256 + threadIdx.x;
    if (t >= VV * MM) return;
    int v = t / MM, m = t - v * MM;
    float dx = centers[v * 2 + 0] - S[m * 2 + 0];
    float dy = centers[v * 2 + 1] - S[m * 2 + 1];
    int in = (sqrtf(dx * dx + dy * dy) < RADIUS) ? 1 : 0;
    mask[t] = in;
    if (in) atomicAdd(&maskcnt[v], 1);
}

// ---------------- generic f32 GEMM  C = A @ B^T  (optional row/col scaling) ----------------
// tiles 64x64, BK=16, 256 threads, 4x4 per thread. All dims divide evenly for our uses.
__global__ __launch_bounds__(256) void gemm_nt_kernel(
    const float* __restrict__ A, const float* __restrict__ B, float* __restrict__ C,
    int M, int Nn, int K,
    long strideAz, long strideBz, long strideCz,
    const float* __restrict__ rnA, const float* __restrict__ rnB, int rnStrideZ)
{
    int z = blockIdx.z;
    A += (long)z * strideAz;
    B += (long)z * strideBz;
    C += (long)z * strideCz;
    const int bm = blockIdx.y * 64;
    const int bn = blockIdx.x * 64;
    __shared__ float As[16][64 + 4];
    __shared__ float Bs[16][64 + 4];
    const int tid = threadIdx.x;
    const int tx = tid & 15, ty = tid >> 4;
    const int lr = tid >> 2;          // 0..63
    const int lk = (tid & 3) * 4;     // 0,4,8,12
    float acc[4][4] = {{0.f}};
    for (int k0 = 0; k0 < K; k0 += 16) {
        float4 av = *reinterpret_cast<const float4*>(A + (long)(bm + lr) * K + k0 + lk);
        float4 bv = *reinterpret_cast<const float4*>(B + (long)(bn + lr) * K + k0 + lk);
        As[lk + 0][lr] = av.x; As[lk + 1][lr] = av.y; As[lk + 2][lr] = av.z; As[lk + 3][lr] = av.w;
        Bs[lk + 0][lr] = bv.x; Bs[lk + 1][lr] = bv.y; Bs[lk + 2][lr] = bv.z; Bs[lk + 3][lr] = bv.w;
        __syncthreads();
        #pragma unroll
        for (int kk = 0; kk < 16; ++kk) {
            float a0 = As[kk][ty * 4 + 0], a1 = As[kk][ty * 4 + 1],
                  a2 = As[kk][ty * 4 + 2], a3 = As[kk][ty * 4 + 3];
            float b0 = Bs[kk][tx * 4 + 0], b1 = Bs[kk][tx * 4 + 1],
                  b2 = Bs[kk][tx * 4 + 2], b3 = Bs[kk][tx * 4 + 3];
            acc[0][0] += a0 * b0; acc[0][1] += a0 * b1; acc[0][2] += a0 * b2; acc[0][3] += a0 * b3;
            acc[1][0] += a1 * b0; acc[1][1] += a1 * b1; acc[1][2] += a1 * b2; acc[1][3] += a1 * b3;
            acc[2][0] += a2 * b0; acc[2][1] += a2 * b1; acc[2][2] += a2 * b2; acc[2][3] += a2 * b3;
            acc[3][0] += a3 * b0; acc[3][1] += a3 * b1; acc[3][2] += a3 * b2; acc[3][3] += a3 * b3;
        }
        __syncthreads();
    }
    #pragma unroll
    for (int i = 0; i < 4; ++i) {
        int row = bm + ty * 4 + i;
        float ra = rnA ? rnA[(long)z * rnStrideZ + row] : 1.0f;
        #pragma unroll
        for (int j = 0; j < 4; ++j) {
            int col = bn + tx * 4 + j;
            float rb = rnB ? rnB[(long)z * rnStrideZ + col] : 1.0f;
            C[(long)row * Nn + col] = acc[i][j] * ra * rb;
        }
    }
}

// ---------------- top-5 per row (one wave per row, optional column mask) ----------------
__global__ __launch_bounds__(64) void topk_kernel(
    const float* __restrict__ sim, long simStrideZ, int n,
    const int* __restrict__ mask, int maskStrideZ,
    int* __restrict__ outIdx, int rowsPerZ)
{
    int gb = blockIdx.x;
    int z = gb / rowsPerZ;
    int e = gb - z * rowsPerZ;
    int lane = threadIdx.x;
    const int* mk = mask ? (mask + (long)z * maskStrideZ) : nullptr;
    if (mk && mk[e] == 0) {
        if (lane == 0) {
            #pragma unroll
            for (int r = 0; r < K_HG; ++r) outIdx[(long)gb * K_HG + r] = -1;
        }
        return;
    }
    const float* row = sim + (long)z * simStrideZ + (long)e * n;
    float v[K_HG]; int ix[K_HG];
    #pragma unroll
    for (int r = 0; r < K_HG; ++r) { v[r] = -INFINITY; ix[r] = 0x7fffffff; }
    for (int j = lane; j < n; j += 64) {
        if (mk && mk[j] == 0) continue;
        float s = row[j];
        if (s > v[K_HG - 1]) {
            int p = K_HG - 1;
            #pragma unroll
            for (int q = K_HG - 1; q >= 1; --q) {
                if (s > v[q - 1]) { v[q] = v[q - 1]; ix[q] = ix[q - 1]; p = q - 1; }
                else break;
            }
            v[p] = s; ix[p] = j;
        }
    }
    // merge 64 sorted-5 lists: 5 rounds of wave argmax (tie -> min index)
    for (int r = 0; r < K_HG; ++r) {
        float bv = v[0]; int bi = ix[0];
        for (int off = 32; off > 0; off >>= 1) {
            float ov = __shfl_xor(bv, off, 64);
            int   oi = __shfl_xor(bi, off, 64);
            if (ov > bv || (ov == bv && oi < bi)) { bv = ov; bi = oi; }
        }
        if (lane == 0) outIdx[(long)gb * K_HG + r] = bi;
        if (v[0] == bv && ix[0] == bi) {
            #pragma unroll
            for (int p = 0; p < K_HG - 1; ++p) { v[p] = v[p + 1]; ix[p] = ix[p + 1]; }
            v[K_HG - 1] = -INFINITY; ix[K_HG - 1] = 0x7fffffff;
        }
    }
}

// ---------------- node degrees dv ----------------
__global__ __launch_bounds__(256) void dv_kernel(const int* __restrict__ idx,
                                                 float* __restrict__ dv,
                                                 int totalEdges, int rowsPerZ) {
    int t = blockIdx.x * 256 + threadIdx.x;
    if (t >= totalEdges * K_HG) return;
    int ge = t / K_HG;
    int z = ge / rowsPerZ;
    int m = idx[t];
    if (m < 0 || m >= rowsPerZ) return;
    atomicAdd(&dv[z * rowsPerZ + m], 1.0f);
}

// ---------------- edge sum (H^T Dv^-1/2 Xw / de) + scatter (H @ ...) ----------------
__global__ __launch_bounds__(256) void edge_kernel(
    const int* __restrict__ idx, const float* __restrict__ Xw,
    const float* __restrict__ dv, float* __restrict__ acc,
    int rowsPerZ, int xwStrideZ)
{
    int ge = blockIdx.x;
    int z = ge / rowsPerZ;
    int d = threadIdx.x;
    int mm[K_HG];
    #pragma unroll
    for (int k = 0; k < K_HG; ++k) mm[k] = idx[(long)ge * K_HG + k];
    if (mm[0] < 0) return;   // unmasked ST edge
    float val = 0.0f;
    #pragma unroll
    for (int k = 0; k < K_HG; ++k) {
        int m = mm[k];
        if (m < 0 || m >= rowsPerZ) continue;
        float w = rsqrtf(fmaxf(dv[z * rowsPerZ + m], EPSF));
        val += w * Xw[(long)(z * xwStrideZ + m) * D_OUT + d];
    }
    val *= (1.0f / (float)K_HG);   // de = 5
    #pragma unroll
    for (int k = 0; k < K_HG; ++k) {
        int m = mm[k];
        if (m < 0 || m >= rowsPerZ) continue;
        atomicAdd(&acc[(long)(z * rowsPerZ + m) * D_OUT + d], val);
    }
}

// ---------------- Dv^-1/2 scale + GELU + partial pool over row chunks ----------------
__global__ __launch_bounds__(256) void pool_partial_kernel(
    const float* __restrict__ acc, const float* __restrict__ dv,
    const int* __restrict__ mask, float* __restrict__ partial,
    int rowsPerZ, int nchunks)
{
    int blk = blockIdx.x;                 // z * nchunks + c
    int z = blk / nchunks, c = blk - z * nchunks;
    int d = threadIdx.x;
    int i0 = c * POOL_CHUNK;
    float s = 0.0f;
    #pragma unroll
    for (int i = 0; i < POOL_CHUNK; ++i) {
        int g = z * rowsPerZ + i0 + i;
        if (mask && mask[g] == 0) continue;
        float w = rsqrtf(fmaxf(dv[g], EPSF));
        float x = w * acc[(long)g * D_OUT + d];
        s += 0.5f * x * (1.0f + erff(x * 0.70710678118654752f));   // exact GELU
    }
    partial[(long)blk * D_OUT + d] = s;
}

__global__ __launch_bounds__(256) void pool_reduce_kernel(
    const float* __restrict__ partial, const int* __restrict__ maskcnt,
    float* __restrict__ zout, int nchunks, int rowsPerZ)
{
    int z = blockIdx.x, d = threadIdx.x;
    float s = 0.0f;
    for (int c = 0; c < nchunks; ++c)
        s += partial[(long)(z * nchunks + c) * D_OUT + d];
    float denom = maskcnt ? (float)maskcnt[z] : (float)rowsPerZ;
    zout[z * D_OUT + d] = s / denom;
}

// ---------------- final contrastive loss ----------------
__global__ __launch_bounds__(64) void final_kernel(const float* __restrict__ zhe,
                                                   const float* __restrict__ zst,
                                                   float* __restrict__ out) {
    __shared__ float he[VV][D_OUT];
    __shared__ float st[VV][D_OUT];
    __shared__ float lg[VV][VV];
    __shared__ float rn_he[VV], rn_st[VV];
    int t = threadIdx.x;
    for (int i = t; i < VV * D_OUT; i += 64) {
        he[i >> 8][i & 255] = zhe[i];
        st[i >> 8][i & 255] = zst[i];
    }
    __syncthreads();
    if (t < VV) {
        float s = 0.0f;
        for (int d2 = 0; d2 < D_OUT; ++d2) s += he[t][d2] * he[t][d2];
        rn_he[t] = 1.0f / fmaxf(sqrtf(s), EPSF);
    } else if (t < 2 * VV) {
        int v = t - VV; float s = 0.0f;
        for (int d2 = 0; d2 < D_OUT; ++d2) s += st[v][d2] * st[v][d2];
        rn_st[v] = 1.0f / fmaxf(sqrtf(s), EPSF);
    }
    __syncthreads();
    int v = t >> 3, w2 = t & 7;
    float dot = 0.0f;
    for (int d2 = 0; d2 < D_OUT; ++d2) dot += he[v][d2] * st[w2][d2];
    lg[v][w2] = dot * rn_he[v] * rn_st[w2] / TEMP;
    __syncthreads();
    if (t == 0) {
        float l1 = 0.0f, l2 = 0.0f;
        for (int i = 0; i < VV; ++i) {
            float mx = -1e30f;
            for (int j = 0; j < VV; ++j) mx = fmaxf(mx, lg[i][j]);
            float se = 0.0f;
            for (int j = 0; j < VV; ++j) se += expf(lg[i][j] - mx);
            l1 += lg[i][i] - (mx + logf(se));
            float mx2 = -1e30f;
            for (int j = 0; j < VV; ++j) mx2 = fmaxf(mx2, lg[j][i]);
            float se2 = 0.0f;
            for (int j = 0; j < VV; ++j) se2 += expf(lg[j][i] - mx2);
            l2 += lg[i][i] - (mx2 + logf(se2));
        }
        out[0] = 0.5f * (-(l1 / (float)VV) - (l2 / (float)VV));
    }
}

// ---------------- launch ----------------
extern "C" void kernel_launch(void* const* d_in, const int* in_sizes, int n_in,
                              void* d_out, int out_size, void* d_ws, size_t ws_size,
                              hipStream_t stream) {
    const float* F    = (const float*)d_in[0];
    const float* T    = (const float*)d_in[1];
    // d_in[2]: region_indices (int32) — regions are contiguous equal blocks; unused
    const float* E    = (const float*)d_in[3];
    const float* S    = (const float*)d_in[4];
    const float* W_he = (const float*)d_in[5];
    const float* W_st = (const float*)d_in[6];
    float* out = (float*)d_out;

    size_t off = 0;
    auto take = [&](size_t bytes) -> void* {
        void* p = (char*)d_ws + off;
        off += (bytes + 255) & ~(size_t)255;
        return p;
    };
    float* Xw_he   = (float*)take((size_t)NN * D_OUT * 4);        // 8 MB
    float* Xw_st   = (float*)take((size_t)MM * D_OUT * 4);        // 2 MB
    float* rnF     = (float*)take((size_t)NN * 4);
    float* rnE     = (float*)take((size_t)MM * 4);
    float* centers = (float*)take((size_t)VV * 2 * 4);
    int*   mask    = (int*)  take((size_t)VV * MM * 4);
    int*   maskcnt = (int*)  take((size_t)VV * 4);
    float* he_sim  = (float*)take((size_t)VV * PP * PP * 4);      // 32 MB
    float* st_sim  = (float*)take((size_t)MM * MM * 4);           // 16 MB
    int*   he_idx  = (int*)  take((size_t)NN * K_HG * 4);
    int*   st_idx  = (int*)  take((size_t)VV * MM * K_HG * 4);
    float* he_dv   = (float*)take((size_t)NN * 4);
    float* st_dv   = (float*)take((size_t)VV * MM * 4);
    float* he_acc  = (float*)take((size_t)NN * D_OUT * 4);        // 8 MB
    float* st_acc  = (float*)take((size_t)VV * MM * D_OUT * 4);   // 16 MB
    float* z_he    = (float*)take((size_t)VV * D_OUT * 4);
    float* z_st    = (float*)take((size_t)VV * D_OUT * 4);
    const int he_nchunks = PP / POOL_CHUNK;   // 64
    const int st_nchunks = MM / POOL_CHUNK;   // 128
    float* he_part = (float*)take((size_t)VV * he_nchunks * D_OUT * 4);  // 512 KB
    float* st_part = (float*)take((size_t)VV * st_nchunks * D_OUT * 4);  // 1 MB

    // norms + geometry
    rownorm_kernel<<<NN, 256, 0, stream>>>(F, rnF, HE_DIM);
    rownorm_kernel<<<MM, 256, 0, stream>>>(E, rnE, ST_DIM);
    centers_kernel<<<VV, 256, 0, stream>>>(T, centers);
    hipMemsetAsync(maskcnt, 0, VV * 4, stream);
    mask_kernel<<<(VV * MM + 255) / 256, 256, 0, stream>>>(centers, S, mask, maskcnt);

    // projections Xw = X @ W^T
    {
        dim3 g(D_OUT / 64, NN / 64, 1);
        gemm_nt_kernel<<<g, 256, 0, stream>>>(F, W_he, Xw_he, NN, D_OUT, HE_DIM,
                                              0, 0, 0, nullptr, nullptr, 0);
    }
    {
        dim3 g(D_OUT / 64, MM / 64, 1);
        gemm_nt_kernel<<<g, 256, 0, stream>>>(E, W_st, Xw_st, MM, D_OUT, ST_DIM,
                                              0, 0, 0, nullptr, nullptr, 0);
    }
    // scaled Grams (cosine sims)
    {
        dim3 g(PP / 64, PP / 64, VV);
        gemm_nt_kernel<<<g, 256, 0, stream>>>(F, F, he_sim, PP, PP, HE_DIM,
                                              (long)PP * HE_DIM, (long)PP * HE_DIM,
                                              (long)PP * PP, rnF, rnF, PP);
    }
    {
        dim3 g(MM / 64, MM / 64, 1);
        gemm_nt_kernel<<<g, 256, 0, stream>>>(E, E, st_sim, MM, MM, ST_DIM,
                                              0, 0, 0, rnE, rnE, 0);
    }
    // top-5
    topk_kernel<<<NN, 64, 0, stream>>>(he_sim, (long)PP * PP, PP, nullptr, 0, he_idx, PP);
    topk_kernel<<<VV * MM, 64, 0, stream>>>(st_sim, 0, MM, mask, MM, st_idx, MM);

    // degrees
    hipMemsetAsync(he_dv, 0, (size_t)NN * 4, stream);
    hipMemsetAsync(st_dv, 0, (size_t)VV * MM * 4, stream);
    dv_kernel<<<(NN * K_HG + 255) / 256, 256, 0, stream>>>(he_idx, he_dv, NN, PP);
    dv_kernel<<<(VV * MM * K_HG + 255) / 256, 256, 0, stream>>>(st_idx, st_dv, VV * MM, MM);

    // conv: edge sums + scatter
    hipMemsetAsync(he_acc, 0, (size_t)NN * D_OUT * 4, stream);
    hipMemsetAsync(st_acc, 0, (size_t)VV * MM * D_OUT * 4, stream);
    edge_kernel<<<NN, 256, 0, stream>>>(he_idx, Xw_he, he_dv, he_acc, PP, PP);
    edge_kernel<<<VV * MM, 256, 0, stream>>>(st_idx, Xw_st, st_dv, st_acc, MM, 0);

    // gelu + pool (two-stage, parallel over row chunks)
    pool_partial_kernel<<<VV * he_nchunks, 256, 0, stream>>>(he_acc, he_dv, nullptr, he_part, PP, he_nchunks);
    pool_partial_kernel<<<VV * st_nchunks, 256, 0, stream>>>(st_acc, st_dv, mask, st_part, MM, st_nchunks);
    pool_reduce_kernel<<<VV, 256, 0, stream>>>(he_part, nullptr, z_he, he_nchunks, PP);
    pool_reduce_kernel<<<VV, 256, 0, stream>>>(st_part, maskcnt, z_st, st_nchunks, MM);

    // loss
    final_kernel<<<1, 64, 0, stream>>>(z_he, z_st, out);
}

// Round 3
// 485.429 us; speedup vs baseline: 2.3491x; 1.3364x over previous
//
#include <hip/hip_runtime.h>
#include <hip/hip_bf16.h>
#include <math.h>

// ---------------- problem constants ----------------
#define NN      8192
#define VV      8
#define PP      1024      // N / V
#define MM      2048
#define HE_DIM  1024
#define ST_DIM  512
#define D_OUT   256
#define K_HG    5
#define RADIUS  150.0f
#define TEMP    0.07f
#define EPSF    1e-12f

#define POOL_CHUNK 16

typedef __bf16 bf16x8 __attribute__((ext_vector_type(8)));
typedef float  f32x4  __attribute__((ext_vector_type(4)));
typedef unsigned short ushort_t;

typedef __attribute__((address_space(1))) void gvoid;
typedef __attribute__((address_space(3))) void svoid;
#define GLOAD16(g, l) __builtin_amdgcn_global_load_lds((gvoid*)(g), (svoid*)(l), 16, 0, 0)

// ---------------- f32 -> (hi,lo) bf16 split:  Y[r][k]=hi, Y[r][K+k]=lo ----------------
__global__ __launch_bounds__(256) void split_kernel(const float* __restrict__ X,
                                                    ushort_t* __restrict__ Y,
                                                    long total, int K) {
    long n4 = total >> 2;
    for (long i4 = (long)blockIdx.x * 256 + threadIdx.x; i4 < n4;
         i4 += (long)gridDim.x * 256) {
        float4 x = reinterpret_cast<const float4*>(X)[i4];
        long e0 = i4 << 2;
        long r = e0 / K;
        int  k = (int)(e0 - r * (long)K);
        float xs[4] = {x.x, x.y, x.z, x.w};
        ushort_t hs[4], ls[4];
        #pragma unroll
        for (int j = 0; j < 4; ++j) {
            unsigned int b  = __float_as_uint(xs[j]);
            unsigned int hu = (b + 0x7fffu + ((b >> 16) & 1u)) >> 16;   // RNE bf16
            hs[j] = (ushort_t)hu;
            float hf = __uint_as_float(hu << 16);
            float l  = xs[j] - hf;                                       // exact
            unsigned int lb = __float_as_uint(l);
            unsigned int lu = (lb + 0x7fffu + ((lb >> 16) & 1u)) >> 16;
            ls[j] = (ushort_t)lu;
        }
        ushort_t* rowp = Y + r * 2L * K;
        *reinterpret_cast<ushort4*>(rowp + k)     = make_ushort4(hs[0], hs[1], hs[2], hs[3]);
        *reinterpret_cast<ushort4*>(rowp + K + k) = make_ushort4(ls[0], ls[1], ls[2], ls[3]);
    }
}

// ---------------- row L2 norm reciprocal (from original f32) ----------------
__global__ __launch_bounds__(256) void rownorm_kernel(const float* __restrict__ A,
                                                      float* __restrict__ rn, int K) {
    int row = blockIdx.x;
    const float* a = A + (long)row * K;
    float s = 0.0f;
    for (int j = threadIdx.x; j < K; j += 256) { float x = a[j]; s += x * x; }
    __shared__ float red[256];
    red[threadIdx.x] = s; __syncthreads();
    for (int o = 128; o > 0; o >>= 1) {
        if (threadIdx.x < o) red[threadIdx.x] += red[threadIdx.x + o];
        __syncthreads();
    }
    if (threadIdx.x == 0) rn[row] = 1.0f / fmaxf(sqrtf(red[0]), EPSF);
}

// ---------------- region centroids ----------------
__global__ __launch_bounds__(256) void centers_kernel(const float* __restrict__ T,
                                                      float* __restrict__ centers) {
    int v = blockIdx.x;
    float sx = 0.0f, sy = 0.0f;
    for (int i = threadIdx.x; i < PP; i += 256) {
        sx += T[(long)(v * PP + i) * 2 + 0];
        sy += T[(long)(v * PP + i) * 2 + 1];
    }
    __shared__ float rx[256], ry[256];
    rx[threadIdx.x] = sx; ry[threadIdx.x] = sy; __syncthreads();
    for (int o = 128; o > 0; o >>= 1) {
        if (threadIdx.x < o) { rx[threadIdx.x] += rx[threadIdx.x + o]; ry[threadIdx.x] += ry[threadIdx.x + o]; }
        __syncthreads();
    }
    if (threadIdx.x == 0) {
        centers[v * 2 + 0] = rx[0] / (float)PP;
        centers[v * 2 + 1] = ry[0] / (float)PP;
    }
}

// ---------------- radius mask ----------------
__global__ __launch_bounds__(256) void mask_kernel(const float* __restrict__ centers,
                                                   const float* __restrict__ S,
                                                   int* __restrict__ mask,
                                                   int* __restrict__ maskcnt) {
    int t = blockIdx.x * 256 + threadIdx.x;
    if (t >= VV * MM) return;
    int v = t / MM, m = t - v * MM;
    float dx = centers[v * 2 + 0] - S[m * 2 + 0];
    float dy = centers[v * 2 + 1] - S[m * 2 + 1];
    int in = (sqrtf(dx * dx + dy * dy) < RADIUS) ? 1 : 0;
    mask[t] = in;
    if (in) atomicAdd(&maskcnt[v], 1);
}

// ---------------- split-bf16 MFMA GEMM:  C = A @ B^T over 3 hi/lo segments ----------------
// A,B: [rows][2K] bf16 (hi | lo). Segments: (Ahi,Bhi),(Alo,Bhi),(Ahi,Blo).
// Tile 128x128, BK=32, 256 threads (4 waves, 2x2), 16x16x32 MFMA, global_load_lds(16B).
// sym!=0: skip bn<bm blocks, mirror-store (requires rnA==rnB, A==B, M==Nn).
__global__ __launch_bounds__(256) void gemm_mfma_nt3(
    const ushort_t* __restrict__ A, const ushort_t* __restrict__ B, float* __restrict__ C,
    int Nn, int K,
    long sAz, long sBz, long sCz,
    const float* __restrict__ rnA, const float* __restrict__ rnB, int rnStrideZ,
    int sym)
{
    const int bm = blockIdx.y * 128;
    const int bn = blockIdx.x * 128;
    if (sym && bn < bm) return;
    int z = blockIdx.z;
    A += (long)z * sAz; B += (long)z * sBz; C += (long)z * sCz;

    __shared__ ushort_t As[128 * 32];
    __shared__ ushort_t Bs[128 * 32];
    const int tid  = threadIdx.x;
    const int lane = tid & 63, wave = tid >> 6;
    const int wr = wave >> 1, wc = wave & 1;
    const int fr = lane & 15, fg = lane >> 4;

    const long lda = 2L * K;
    // staging geometry: instruction i covers tile bytes [i*4096 + wave*1024 + lane*16)
    const int tb0   = wave * 1024 + lane * 16;
    const int srow0 = tb0 >> 6;         // row of this lane's 16B (64B per tile row)
    const int scole = (tb0 & 63) >> 1;  // element col within 32-elem tile row

    f32x4 acc[4][4] = {};

    #pragma unroll 1
    for (int s = 0; s < 3; ++s) {
        const long aoff = (s == 1) ? (long)K : 0;
        const long boff = (s == 2) ? (long)K : 0;
        for (int kk = 0; kk < K; kk += 32) {
            const ushort_t* ga = A + (long)(bm + srow0) * lda + aoff + kk + scole;
            const ushort_t* gb = B + (long)(bn + srow0) * lda + boff + kk + scole;
            GLOAD16(ga,            (char*)As + wave * 1024);
            GLOAD16(ga + 64 * lda, (char*)As + wave * 1024 + 4096);
            GLOAD16(gb,            (char*)Bs + wave * 1024);
            GLOAD16(gb + 64 * lda, (char*)Bs + wave * 1024 + 4096);
            __syncthreads();
            bf16x8 af[4], bfv[4];
            #pragma unroll
            for (int m = 0; m < 4; ++m)
                af[m] = *reinterpret_cast<const bf16x8*>(As + (wr * 64 + m * 16 + fr) * 32 + fg * 8);
            #pragma unroll
            for (int n = 0; n < 4; ++n)
                bfv[n] = *reinterpret_cast<const bf16x8*>(Bs + (wc * 64 + n * 16 + fr) * 32 + fg * 8);
            #pragma unroll
            for (int m = 0; m < 4; ++m)
                #pragma unroll
                for (int n = 0; n < 4; ++n)
                    acc[m][n] = __builtin_amdgcn_mfma_f32_16x16x32_bf16(af[m], bfv[n], acc[m][n], 0, 0, 0);
            __syncthreads();
        }
    }

    #pragma unroll
    for (int m = 0; m < 4; ++m) {
        #pragma unroll
        for (int r = 0; r < 4; ++r) {
            int row = bm + wr * 64 + m * 16 + fg * 4 + r;
            float ra = rnA ? rnA[(long)z * rnStrideZ + row] : 1.0f;
            #pragma unroll
            for (int n = 0; n < 4; ++n) {
                int col = bn + wc * 64 + n * 16 + fr;
                float rb = rnB ? rnB[(long)z * rnStrideZ + col] : 1.0f;
                float val = acc[m][n][r] * ra * rb;
                C[(long)row * Nn + col] = val;
                if (sym && bn > bm) C[(long)col * Nn + row] = val;
            }
        }
    }
}

// ---------------- top-5 per row (one wave per row, optional column mask) ----------------
__global__ __launch_bounds__(64) void topk_kernel(
    const float* __restrict__ sim, long simStrideZ, int n,
    const int* __restrict__ mask, int maskStrideZ,
    int* __restrict__ outIdx, int rowsPerZ)
{
    int gb = blockIdx.x;
    int z = gb / rowsPerZ;
    int e = gb - z * rowsPerZ;
    int lane = threadIdx.x;
    const int* mk = mask ? (mask + (long)z * maskStrideZ) : nullptr;
    if (mk && mk[e] == 0) {
        if (lane == 0) {
            #pragma unroll
            for (int r = 0; r < K_HG; ++r) outIdx[(long)gb * K_HG + r] = -1;
        }
        return;
    }
    const float* row = sim + (long)z * simStrideZ + (long)e * n;
    float v[K_HG]; int ix[K_HG];
    #pragma unroll
    for (int r = 0; r < K_HG; ++r) { v[r] = -INFINITY; ix[r] = 0x7fffffff; }
    for (int j = lane; j < n; j += 64) {
        if (mk && mk[j] == 0) continue;
        float s = row[j];
        if (s > v[K_HG - 1]) {
            int p = K_HG - 1;
            #pragma unroll
            for (int q = K_HG - 1; q >= 1; --q) {
                if (s > v[q - 1]) { v[q] = v[q - 1]; ix[q] = ix[q - 1]; p = q - 1; }
                else break;
            }
            v[p] = s; ix[p] = j;
        }
    }
    for (int r = 0; r < K_HG; ++r) {
        float bv = v[0]; int bi = ix[0];
        for (int off = 32; off > 0; off >>= 1) {
            float ov = __shfl_xor(bv, off, 64);
            int   oi = __shfl_xor(bi, off, 64);
            if (ov > bv || (ov == bv && oi < bi)) { bv = ov; bi = oi; }
        }
        if (lane == 0) outIdx[(long)gb * K_HG + r] = bi;
        if (v[0] == bv && ix[0] == bi) {
            #pragma unroll
            for (int p = 0; p < K_HG - 1; ++p) { v[p] = v[p + 1]; ix[p] = ix[p + 1]; }
            v[K_HG - 1] = -INFINITY; ix[K_HG - 1] = 0x7fffffff;
        }
    }
}

// ---------------- node degrees dv ----------------
__global__ __launch_bounds__(256) void dv_kernel(const int* __restrict__ idx,
                                                 float* __restrict__ dv,
                                                 int totalEdges, int rowsPerZ) {
    int t = blockIdx.x * 256 + threadIdx.x;
    if (t >= totalEdges * K_HG) return;
    int ge = t / K_HG;
    int z = ge / rowsPerZ;
    int m = idx[t];
    if (m < 0 || m >= rowsPerZ) return;
    atomicAdd(&dv[z * rowsPerZ + m], 1.0f);
}

// ---------------- edge sum + scatter ----------------
__global__ __launch_bounds__(256) void edge_kernel(
    const int* __restrict__ idx, const float* __restrict__ Xw,
    const float* __restrict__ dv, float* __restrict__ acc,
    int rowsPerZ, int xwStrideZ)
{
    int ge = blockIdx.x;
    int z = ge / rowsPerZ;
    int d = threadIdx.x;
    int mm[K_HG];
    #pragma unroll
    for (int k = 0; k < K_HG; ++k) mm[k] = idx[(long)ge * K_HG + k];
    if (mm[0] < 0) return;
    float val = 0.0f;
    #pragma unroll
    for (int k = 0; k < K_HG; ++k) {
        int m = mm[k];
        if (m < 0 || m >= rowsPerZ) continue;
        float w = rsqrtf(fmaxf(dv[z * rowsPerZ + m], EPSF));
        val += w * Xw[(long)(z * xwStrideZ + m) * D_OUT + d];
    }
    val *= (1.0f / (float)K_HG);
    #pragma unroll
    for (int k = 0; k < K_HG; ++k) {
        int m = mm[k];
        if (m < 0 || m >= rowsPerZ) continue;
        atomicAdd(&acc[(long)(z * rowsPerZ + m) * D_OUT + d], val);
    }
}

// ---------------- Dv^-1/2 scale + GELU + partial pool ----------------
__global__ __launch_bounds__(256) void pool_partial_kernel(
    const float* __restrict__ acc, const float* __restrict__ dv,
    const int* __restrict__ mask, float* __restrict__ partial,
    int rowsPerZ, int nchunks)
{
    int blk = blockIdx.x;
    int z = blk / nchunks, c = blk - z * nchunks;
    int d = threadIdx.x;
    int i0 = c * POOL_CHUNK;
    float s = 0.0f;
    #pragma unroll
    for (int i = 0; i < POOL_CHUNK; ++i) {
        int g = z * rowsPerZ + i0 + i;
        if (mask && mask[g] == 0) continue;
        float w = rsqrtf(fmaxf(dv[g], EPSF));
        float x = w * acc[(long)g * D_OUT + d];
        s += 0.5f * x * (1.0f + erff(x * 0.70710678118654752f));
    }
    partial[(long)blk * D_OUT + d] = s;
}

__global__ __launch_bounds__(256) void pool_reduce_kernel(
    const float* __restrict__ partial, const int* __restrict__ maskcnt,
    float* __restrict__ zout, int nchunks, int rowsPerZ)
{
    int z = blockIdx.x, d = threadIdx.x;
    float s = 0.0f;
    for (int c = 0; c < nchunks; ++c)
        s += partial[(long)(z * nchunks + c) * D_OUT + d];
    float denom = maskcnt ? (float)maskcnt[z] : (float)rowsPerZ;
    zout[z * D_OUT + d] = s / denom;
}

// ---------------- final contrastive loss ----------------
__global__ __launch_bounds__(64) void final_kernel(const float* __restrict__ zhe,
                                                   const float* __restrict__ zst,
                                                   float* __restrict__ out) {
    __shared__ float he[VV][D_OUT];
    __shared__ float st[VV][D_OUT];
    __shared__ float lg[VV][VV];
    __shared__ float rn_he[VV], rn_st[VV];
    int t = threadIdx.x;
    for (int i = t; i < VV * D_OUT; i += 64) {
        he[i >> 8][i & 255] = zhe[i];
        st[i >> 8][i & 255] = zst[i];
    }
    __syncthreads();
    if (t < VV) {
        float s = 0.0f;
        for (int d2 = 0; d2 < D_OUT; ++d2) s += he[t][d2] * he[t][d2];
        rn_he[t] = 1.0f / fmaxf(sqrtf(s), EPSF);
    } else if (t < 2 * VV) {
        int v = t - VV; float s = 0.0f;
        for (int d2 = 0; d2 < D_OUT; ++d2) s += st[v][d2] * st[v][d2];
        rn_st[v] = 1.0f / fmaxf(sqrtf(s), EPSF);
    }
    __syncthreads();
    int v = t >> 3, w2 = t & 7;
    float dot = 0.0f;
    for (int d2 = 0; d2 < D_OUT; ++d2) dot += he[v][d2] * st[w2][d2];
    lg[v][w2] = dot * rn_he[v] * rn_st[w2] / TEMP;
    __syncthreads();
    if (t == 0) {
        float l1 = 0.0f, l2 = 0.0f;
        for (int i = 0; i < VV; ++i) {
            float mx = -1e30f;
            for (int j = 0; j < VV; ++j) mx = fmaxf(mx, lg[i][j]);
            float se = 0.0f;
            for (int j = 0; j < VV; ++j) se += expf(lg[i][j] - mx);
            l1 += lg[i][i] - (mx + logf(se));
            float mx2 = -1e30f;
            for (int j = 0; j < VV; ++j) mx2 = fmaxf(mx2, lg[j][i]);
            float se2 = 0.0f;
            for (int j = 0; j < VV; ++j) se2 += expf(lg[j][i] - mx2);
            l2 += lg[i][i] - (mx2 + logf(se2));
        }
        out[0] = 0.5f * (-(l1 / (float)VV) - (l2 / (float)VV));
    }
}

// ---------------- launch ----------------
extern "C" void kernel_launch(void* const* d_in, const int* in_sizes, int n_in,
                              void* d_out, int out_size, void* d_ws, size_t ws_size,
                              hipStream_t stream) {
    const float* F    = (const float*)d_in[0];
    const float* T    = (const float*)d_in[1];
    const float* E    = (const float*)d_in[3];
    const float* S    = (const float*)d_in[4];
    const float* W_he = (const float*)d_in[5];
    const float* W_st = (const float*)d_in[6];
    float* out = (float*)d_out;

    size_t off = 0;
    auto take = [&](size_t bytes) -> void* {
        void* p = (char*)d_ws + off;
        off += (bytes + 255) & ~(size_t)255;
        return p;
    };
    ushort_t* Fs    = (ushort_t*)take((size_t)NN * 2 * HE_DIM * 2);   // 33.5 MB
    ushort_t* Es    = (ushort_t*)take((size_t)MM * 2 * ST_DIM * 2);   // 4.2 MB
    ushort_t* Whes  = (ushort_t*)take((size_t)D_OUT * 2 * HE_DIM * 2);
    ushort_t* Wsts  = (ushort_t*)take((size_t)D_OUT * 2 * ST_DIM * 2);
    float* Xw_he    = (float*)take((size_t)NN * D_OUT * 4);           // 8 MB
    float* Xw_st    = (float*)take((size_t)MM * D_OUT * 4);           // 2 MB
    float* rnF      = (float*)take((size_t)NN * 4);
    float* rnE      = (float*)take((size_t)MM * 4);
    float* centers  = (float*)take((size_t)VV * 2 * 4);
    int*   mask     = (int*)  take((size_t)VV * MM * 4);
    int*   maskcnt  = (int*)  take((size_t)VV * 4);
    float* he_sim   = (float*)take((size_t)VV * PP * PP * 4);         // 32 MB
    float* st_sim   = (float*)take((size_t)MM * MM * 4);              // 16 MB
    int*   he_idx   = (int*)  take((size_t)NN * K_HG * 4);
    int*   st_idx   = (int*)  take((size_t)VV * MM * K_HG * 4);
    float* he_dv    = (float*)take((size_t)NN * 4);
    float* st_dv    = (float*)take((size_t)VV * MM * 4);
    float* he_acc   = (float*)take((size_t)NN * D_OUT * 4);           // 8 MB
    float* st_acc   = (float*)take((size_t)VV * MM * D_OUT * 4);      // 16 MB
    float* z_he     = (float*)take((size_t)VV * D_OUT * 4);
    float* z_st     = (float*)take((size_t)VV * D_OUT * 4);
    const int he_nchunks = PP / POOL_CHUNK;
    const int st_nchunks = MM / POOL_CHUNK;
    float* he_part = (float*)take((size_t)VV * he_nchunks * D_OUT * 4);
    float* st_part = (float*)take((size_t)VV * st_nchunks * D_OUT * 4);

    // split f32 -> hi/lo bf16
    split_kernel<<<2048, 256, 0, stream>>>(F, Fs, (long)NN * HE_DIM, HE_DIM);
    split_kernel<<<1024, 256, 0, stream>>>(E, Es, (long)MM * ST_DIM, ST_DIM);
    split_kernel<<<256, 256, 0, stream>>>(W_he, Whes, (long)D_OUT * HE_DIM, HE_DIM);
    split_kernel<<<128, 256, 0, stream>>>(W_st, Wsts, (long)D_OUT * ST_DIM, ST_DIM);

    // norms + geometry
    rownorm_kernel<<<NN, 256, 0, stream>>>(F, rnF, HE_DIM);
    rownorm_kernel<<<MM, 256, 0, stream>>>(E, rnE, ST_DIM);
    centers_kernel<<<VV, 256, 0, stream>>>(T, centers);
    hipMemsetAsync(maskcnt, 0, VV * 4, stream);
    mask_kernel<<<(VV * MM + 255) / 256, 256, 0, stream>>>(centers, S, mask, maskcnt);

    // projections Xw = X @ W^T   (split-bf16 MFMA)
    {
        dim3 g(D_OUT / 128, NN / 128, 1);
        gemm_mfma_nt3<<<g, 256, 0, stream>>>(Fs, Whes, Xw_he, D_OUT, HE_DIM,
                                             0, 0, 0, nullptr, nullptr, 0, 0);
    }
    {
        dim3 g(D_OUT / 128, MM / 128, 1);
        gemm_mfma_nt3<<<g, 256, 0, stream>>>(Es, Wsts, Xw_st, D_OUT, ST_DIM,
                                             0, 0, 0, nullptr, nullptr, 0, 0);
    }
    // cosine-sim Grams (symmetric)
    {
        dim3 g(PP / 128, PP / 128, VV);
        gemm_mfma_nt3<<<g, 256, 0, stream>>>(Fs, Fs, he_sim, PP, HE_DIM,
                                             (long)PP * 2 * HE_DIM, (long)PP * 2 * HE_DIM,
                                             (long)PP * PP, rnF, rnF, PP, 1);
    }
    {
        dim3 g(MM / 128, MM / 128, 1);
        gemm_mfma_nt3<<<g, 256, 0, stream>>>(Es, Es, st_sim, MM, ST_DIM,
                                             0, 0, 0, rnE, rnE, 0, 1);
    }

    // top-5
    topk_kernel<<<NN, 64, 0, stream>>>(he_sim, (long)PP * PP, PP, nullptr, 0, he_idx, PP);
    topk_kernel<<<VV * MM, 64, 0, stream>>>(st_sim, 0, MM, mask, MM, st_idx, MM);

    // degrees
    hipMemsetAsync(he_dv, 0, (size_t)NN * 4, stream);
    hipMemsetAsync(st_dv, 0, (size_t)VV * MM * 4, stream);
    dv_kernel<<<(NN * K_HG + 255) / 256, 256, 0, stream>>>(he_idx, he_dv, NN, PP);
    dv_kernel<<<(VV * MM * K_HG + 255) / 256, 256, 0, stream>>>(st_idx, st_dv, VV * MM, MM);

    // conv: edge sums + scatter
    hipMemsetAsync(he_acc, 0, (size_t)NN * D_OUT * 4, stream);
    hipMemsetAsync(st_acc, 0, (size_t)VV * MM * D_OUT * 4, stream);
    edge_kernel<<<NN, 256, 0, stream>>>(he_idx, Xw_he, he_dv, he_acc, PP, PP);
    edge_kernel<<<VV * MM, 256, 0, stream>>>(st_idx, Xw_st, st_dv, st_acc, MM, 0);

    // gelu + pool
    pool_partial_kernel<<<VV * he_nchunks, 256, 0, stream>>>(he_acc, he_dv, nullptr, he_part, PP, he_nchunks);
    pool_partial_kernel<<<VV * st_nchunks, 256, 0, stream>>>(st_acc, st_dv, mask, st_part, MM, st_nchunks);
    pool_reduce_kernel<<<VV, 256, 0, stream>>>(he_part, nullptr, z_he, he_nchunks, PP);
    pool_reduce_kernel<<<VV, 256, 0, stream>>>(st_part, maskcnt, z_st, st_nchunks, MM);

    // loss
    final_kernel<<<1, 64, 0, stream>>>(z_he, z_st, out);
}

// Round 4
// 365.306 us; speedup vs baseline: 3.1216x; 1.3288x over previous
//
#include <hip/hip_runtime.h>
#include <hip/hip_bf16.h>
#include <math.h>

// ---------------- problem constants ----------------
#define NN      8192
#define VV      8
#define PP      1024      // N / V
#define MM      2048
#define HE_DIM  1024
#define ST_DIM  512
#define D_OUT   256
#define K_HG    5
#define RADIUS  150.0f
#define TEMP    0.07f
#define EPSF    1e-12f

#define POOL_CHUNK 16

// grouped-GEMM block ranges
#define HE_TRI   36                 // 8x8 upper triangle
#define ST_TRI   136                // 16x16 upper triangle
#define NB_HE    (VV * HE_TRI)      // 288
#define NB_ST    ST_TRI             // 136
#define NB_PH    ((NN / 128) * (D_OUT / 128))   // 128
#define NB_PS    ((MM / 128) * (D_OUT / 128))   // 32
#define NB_ALL   (NB_HE + NB_ST + NB_PH + NB_PS) // 584

typedef __bf16 bf16x8 __attribute__((ext_vector_type(8)));
typedef float  f32x4  __attribute__((ext_vector_type(4)));
typedef unsigned short ushort_t;

typedef __attribute__((address_space(1))) void gvoid;
typedef __attribute__((address_space(3))) void svoid;
#define GLOAD16(g, l) __builtin_amdgcn_global_load_lds((gvoid*)(g), (svoid*)(l), 16, 0, 0)

// ---------------- f32 -> (hi,lo) bf16 split:  Y[r][k]=hi, Y[r][K+k]=lo ----------------
__global__ __launch_bounds__(256) void split_kernel(const float* __restrict__ X,
                                                    ushort_t* __restrict__ Y,
                                                    long total, int K) {
    long n4 = total >> 2;
    for (long i4 = (long)blockIdx.x * 256 + threadIdx.x; i4 < n4;
         i4 += (long)gridDim.x * 256) {
        float4 x = reinterpret_cast<const float4*>(X)[i4];
        long e0 = i4 << 2;
        long r = e0 / K;
        int  k = (int)(e0 - r * (long)K);
        float xs[4] = {x.x, x.y, x.z, x.w};
        ushort_t hs[4], ls[4];
        #pragma unroll
        for (int j = 0; j < 4; ++j) {
            unsigned int b  = __float_as_uint(xs[j]);
            unsigned int hu = (b + 0x7fffu + ((b >> 16) & 1u)) >> 16;   // RNE bf16
            hs[j] = (ushort_t)hu;
            float hf = __uint_as_float(hu << 16);
            float l  = xs[j] - hf;                                       // exact
            unsigned int lb = __float_as_uint(l);
            unsigned int lu = (lb + 0x7fffu + ((lb >> 16) & 1u)) >> 16;
            ls[j] = (ushort_t)lu;
        }
        ushort_t* rowp = Y + r * 2L * K;
        *reinterpret_cast<ushort4*>(rowp + k)     = make_ushort4(hs[0], hs[1], hs[2], hs[3]);
        *reinterpret_cast<ushort4*>(rowp + K + k) = make_ushort4(ls[0], ls[1], ls[2], ls[3]);
    }
}

// ---------------- row L2 norm reciprocal (from original f32) ----------------
__global__ __launch_bounds__(256) void rownorm_kernel(const float* __restrict__ A,
                                                      float* __restrict__ rn, int K) {
    int row = blockIdx.x;
    const float* a = A + (long)row * K;
    float s = 0.0f;
    for (int j = threadIdx.x; j < K; j += 256) { float x = a[j]; s += x * x; }
    __shared__ float red[256];
    red[threadIdx.x] = s; __syncthreads();
    for (int o = 128; o > 0; o >>= 1) {
        if (threadIdx.x < o) red[threadIdx.x] += red[threadIdx.x + o];
        __syncthreads();
    }
    if (threadIdx.x == 0) rn[row] = 1.0f / fmaxf(sqrtf(red[0]), EPSF);
}

// ---------------- region centroids ----------------
__global__ __launch_bounds__(256) void centers_kernel(const float* __restrict__ T,
                                                      float* __restrict__ centers) {
    int v = blockIdx.x;
    float sx = 0.0f, sy = 0.0f;
    for (int i = threadIdx.x; i < PP; i += 256) {
        sx += T[(long)(v * PP + i) * 2 + 0];
        sy += T[(long)(v * PP + i) * 2 + 1];
    }
    __shared__ float rx[256], ry[256];
    rx[threadIdx.x] = sx; ry[threadIdx.x] = sy; __syncthreads();
    for (int o = 128; o > 0; o >>= 1) {
        if (threadIdx.x < o) { rx[threadIdx.x] += rx[threadIdx.x + o]; ry[threadIdx.x] += ry[threadIdx.x + o]; }
        __syncthreads();
    }
    if (threadIdx.x == 0) {
        centers[v * 2 + 0] = rx[0] / (float)PP;
        centers[v * 2 + 1] = ry[0] / (float)PP;
    }
}

// ---------------- radius mask ----------------
__global__ __launch_bounds__(256) void mask_kernel(const float* __restrict__ centers,
                                                   const float* __restrict__ S,
                                                   int* __restrict__ mask,
                                                   int* __restrict__ maskcnt) {
    int t = blockIdx.x * 256 + threadIdx.x;
    if (t >= VV * MM) return;
    int v = t / MM, m = t - v * MM;
    float dx = centers[v * 2 + 0] - S[m * 2 + 0];
    float dy = centers[v * 2 + 1] - S[m * 2 + 1];
    int in = (sqrtf(dx * dx + dy * dy) < RADIUS) ? 1 : 0;
    mask[t] = in;
    if (in) atomicAdd(&maskcnt[v], 1);
}

// ---------------- grouped split-bf16 MFMA GEMM ----------------
// One launch covers: 8x HE Gram (sym), ST Gram (sym), proj_he, proj_st.
// A,B: [rows][2K] bf16 (hi|lo); segments (Ahi,Bhi),(Alo,Bhi),(Ahi,Blo).
// Tile 128x128, BK=32, 256 threads (4 waves 2x2), 16x16x32 MFMA, global_load_lds(16B).
__global__ __launch_bounds__(256) void gemm_grouped(
    const ushort_t* __restrict__ Fs, const ushort_t* __restrict__ Es,
    const ushort_t* __restrict__ Whes, const ushort_t* __restrict__ Wsts,
    float* __restrict__ he_sim, float* __restrict__ st_sim,
    float* __restrict__ Xw_he, float* __restrict__ Xw_st,
    const float* __restrict__ rnF, const float* __restrict__ rnE)
{
    // ---- block-id -> operation/tile map (all wave-uniform scalar work) ----
    int id = blockIdx.x;
    const ushort_t *A, *B; float *C;
    const float *rA = nullptr, *rB = nullptr;
    int K, Nn, bm, bn, sym;
    if (id < NB_HE) {
        int z = id / HE_TRI, t = id - z * HE_TRI;
        int i = 0;
        while (t >= 8 - i) { t -= 8 - i; ++i; }
        bm = i * 128; bn = (i + t) * 128;
        A = B = Fs + (long)z * PP * 2 * HE_DIM;
        C = he_sim + (long)z * PP * PP;
        rA = rB = rnF + z * PP;
        K = HE_DIM; Nn = PP; sym = 1;
    } else if (id < NB_HE + NB_ST) {
        int t = id - NB_HE;
        int i = 0;
        while (t >= 16 - i) { t -= 16 - i; ++i; }
        bm = i * 128; bn = (i + t) * 128;
        A = B = Es; C = st_sim; rA = rB = rnE;
        K = ST_DIM; Nn = MM; sym = 1;
    } else if (id < NB_HE + NB_ST + NB_PH) {
        int t = id - (NB_HE + NB_ST);
        bm = (t >> 1) * 128; bn = (t & 1) * 128;
        A = Fs; B = Whes; C = Xw_he;
        K = HE_DIM; Nn = D_OUT; sym = 0;
    } else {
        int t = id - (NB_HE + NB_ST + NB_PH);
        bm = (t >> 1) * 128; bn = (t & 1) * 128;
        A = Es; B = Wsts; C = Xw_st;
        K = ST_DIM; Nn = D_OUT; sym = 0;
    }

    __shared__ ushort_t As[128 * 32];
    __shared__ ushort_t Bs[128 * 32];
    const int tid  = threadIdx.x;
    const int lane = tid & 63, wave = tid >> 6;
    const int wr = wave >> 1, wc = wave & 1;
    const int fr = lane & 15, fg = lane >> 4;

    const long lda = 2L * K;
    const int tb0   = wave * 1024 + lane * 16;
    const int srow0 = tb0 >> 6;
    const int scole = (tb0 & 63) >> 1;

    f32x4 acc[4][4] = {};

    #pragma unroll 1
    for (int s = 0; s < 3; ++s) {
        const long aoff = (s == 1) ? (long)K : 0;
        const long boff = (s == 2) ? (long)K : 0;
        for (int kk = 0; kk < K; kk += 32) {
            const ushort_t* ga = A + (long)(bm + srow0) * lda + aoff + kk + scole;
            const ushort_t* gb = B + (long)(bn + srow0) * lda + boff + kk + scole;
            GLOAD16(ga,            (char*)As + wave * 1024);
            GLOAD16(ga + 64 * lda, (char*)As + wave * 1024 + 4096);
            GLOAD16(gb,            (char*)Bs + wave * 1024);
            GLOAD16(gb + 64 * lda, (char*)Bs + wave * 1024 + 4096);
            __syncthreads();
            bf16x8 af[4], bfv[4];
            #pragma unroll
            for (int m = 0; m < 4; ++m)
                af[m] = *reinterpret_cast<const bf16x8*>(As + (wr * 64 + m * 16 + fr) * 32 + fg * 8);
            #pragma unroll
            for (int n = 0; n < 4; ++n)
                bfv[n] = *reinterpret_cast<const bf16x8*>(Bs + (wc * 64 + n * 16 + fr) * 32 + fg * 8);
            #pragma unroll
            for (int m = 0; m < 4; ++m)
                #pragma unroll
                for (int n = 0; n < 4; ++n)
                    acc[m][n] = __builtin_amdgcn_mfma_f32_16x16x32_bf16(af[m], bfv[n], acc[m][n], 0, 0, 0);
            __syncthreads();
        }
    }

    #pragma unroll
    for (int m = 0; m < 4; ++m) {
        #pragma unroll
        for (int r = 0; r < 4; ++r) {
            int row = bm + wr * 64 + m * 16 + fg * 4 + r;
            float ra = rA ? rA[row] : 1.0f;
            #pragma unroll
            for (int n = 0; n < 4; ++n) {
                int col = bn + wc * 64 + n * 16 + fr;
                float rb = rB ? rB[col] : 1.0f;
                float val = acc[m][n][r] * ra * rb;
                C[(long)row * Nn + col] = val;
                if (sym && bn > bm) C[(long)col * Nn + row] = val;
            }
        }
    }
}

// ---------------- top-5 per row (one wave per row, optional column mask) ----------------
__global__ __launch_bounds__(64) void topk_kernel(
    const float* __restrict__ sim, long simStrideZ, int n,
    const int* __restrict__ mask, int maskStrideZ,
    int* __restrict__ outIdx, int rowsPerZ)
{
    int gb = blockIdx.x;
    int z = gb / rowsPerZ;
    int e = gb - z * rowsPerZ;
    int lane = threadIdx.x;
    const int* mk = mask ? (mask + (long)z * maskStrideZ) : nullptr;
    if (mk && mk[e] == 0) {
        if (lane == 0) {
            #pragma unroll
            for (int r = 0; r < K_HG; ++r) outIdx[(long)gb * K_HG + r] = -1;
        }
        return;
    }
    const float* row = sim + (long)z * simStrideZ + (long)e * n;
    float v[K_HG]; int ix[K_HG];
    #pragma unroll
    for (int r = 0; r < K_HG; ++r) { v[r] = -INFINITY; ix[r] = 0x7fffffff; }
    for (int j = lane; j < n; j += 64) {
        if (mk && mk[j] == 0) continue;
        float s = row[j];
        if (s > v[K_HG - 1]) {
            int p = K_HG - 1;
            #pragma unroll
            for (int q = K_HG - 1; q >= 1; --q) {
                if (s > v[q - 1]) { v[q] = v[q - 1]; ix[q] = ix[q - 1]; p = q - 1; }
                else break;
            }
            v[p] = s; ix[p] = j;
        }
    }
    for (int r = 0; r < K_HG; ++r) {
        float bv = v[0]; int bi = ix[0];
        for (int off = 32; off > 0; off >>= 1) {
            float ov = __shfl_xor(bv, off, 64);
            int   oi = __shfl_xor(bi, off, 64);
            if (ov > bv || (ov == bv && oi < bi)) { bv = ov; bi = oi; }
        }
        if (lane == 0) outIdx[(long)gb * K_HG + r] = bi;
        if (v[0] == bv && ix[0] == bi) {
            #pragma unroll
            for (int p = 0; p < K_HG - 1; ++p) { v[p] = v[p + 1]; ix[p] = ix[p + 1]; }
            v[K_HG - 1] = -INFINITY; ix[K_HG - 1] = 0x7fffffff;
        }
    }
}

// ---------------- node degrees dv ----------------
__global__ __launch_bounds__(256) void dv_kernel(const int* __restrict__ idx,
                                                 float* __restrict__ dv,
                                                 int totalEdges, int rowsPerZ) {
    int t = blockIdx.x * 256 + threadIdx.x;
    if (t >= totalEdges * K_HG) return;
    int ge = t / K_HG;
    int z = ge / rowsPerZ;
    int m = idx[t];
    if (m < 0 || m >= rowsPerZ) return;
    atomicAdd(&dv[z * rowsPerZ + m], 1.0f);
}

// ---------------- edge sum + scatter ----------------
__global__ __launch_bounds__(256) void edge_kernel(
    const int* __restrict__ idx, const float* __restrict__ Xw,
    const float* __restrict__ dv, float* __restrict__ acc,
    int rowsPerZ, int xwStrideZ)
{
    int ge = blockIdx.x;
    int z = ge / rowsPerZ;
    int d = threadIdx.x;
    int mm[K_HG];
    #pragma unroll
    for (int k = 0; k < K_HG; ++k) mm[k] = idx[(long)ge * K_HG + k];
    if (mm[0] < 0) return;
    float val = 0.0f;
    #pragma unroll
    for (int k = 0; k < K_HG; ++k) {
        int m = mm[k];
        if (m < 0 || m >= rowsPerZ) continue;
        float w = rsqrtf(fmaxf(dv[z * rowsPerZ + m], EPSF));
        val += w * Xw[(long)(z * xwStrideZ + m) * D_OUT + d];
    }
    val *= (1.0f / (float)K_HG);
    #pragma unroll
    for (int k = 0; k < K_HG; ++k) {
        int m = mm[k];
        if (m < 0 || m >= rowsPerZ) continue;
        atomicAdd(&acc[(long)(z * rowsPerZ + m) * D_OUT + d], val);
    }
}

// ---------------- Dv^-1/2 scale + GELU + partial pool ----------------
__global__ __launch_bounds__(256) void pool_partial_kernel(
    const float* __restrict__ acc, const float* __restrict__ dv,
    const int* __restrict__ mask, float* __restrict__ partial,
    int rowsPerZ, int nchunks)
{
    int blk = blockIdx.x;
    int z = blk / nchunks, c = blk - z * nchunks;
    int d = threadIdx.x;
    int i0 = c * POOL_CHUNK;
    float s = 0.0f;
    #pragma unroll
    for (int i = 0; i < POOL_CHUNK; ++i) {
        int g = z * rowsPerZ + i0 + i;
        if (mask && mask[g] == 0) continue;
        float w = rsqrtf(fmaxf(dv[g], EPSF));
        float x = w * acc[(long)g * D_OUT + d];
        s += 0.5f * x * (1.0f + erff(x * 0.70710678118654752f));
    }
    partial[(long)blk * D_OUT + d] = s;
}

__global__ __launch_bounds__(256) void pool_reduce_kernel(
    const float* __restrict__ partial, const int* __restrict__ maskcnt,
    float* __restrict__ zout, int nchunks, int rowsPerZ)
{
    int z = blockIdx.x, d = threadIdx.x;
    float s = 0.0f;
    for (int c = 0; c < nchunks; ++c)
        s += partial[(long)(z * nchunks + c) * D_OUT + d];
    float denom = maskcnt ? (float)maskcnt[z] : (float)rowsPerZ;
    zout[z * D_OUT + d] = s / denom;
}

// ---------------- final contrastive loss ----------------
__global__ __launch_bounds__(64) void final_kernel(const float* __restrict__ zhe,
                                                   const float* __restrict__ zst,
                                                   float* __restrict__ out) {
    __shared__ float he[VV][D_OUT];
    __shared__ float st[VV][D_OUT];
    __shared__ float lg[VV][VV];
    __shared__ float rn_he[VV], rn_st[VV];
    int t = threadIdx.x;
    for (int i = t; i < VV * D_OUT; i += 64) {
        he[i >> 8][i & 255] = zhe[i];
        st[i >> 8][i & 255] = zst[i];
    }
    __syncthreads();
    if (t < VV) {
        float s = 0.0f;
        for (int d2 = 0; d2 < D_OUT; ++d2) s += he[t][d2] * he[t][d2];
        rn_he[t] = 1.0f / fmaxf(sqrtf(s), EPSF);
    } else if (t < 2 * VV) {
        int v = t - VV; float s = 0.0f;
        for (int d2 = 0; d2 < D_OUT; ++d2) s += st[v][d2] * st[v][d2];
        rn_st[v] = 1.0f / fmaxf(sqrtf(s), EPSF);
    }
    __syncthreads();
    int v = t >> 3, w2 = t & 7;
    float dot = 0.0f;
    for (int d2 = 0; d2 < D_OUT; ++d2) dot += he[v][d2] * st[w2][d2];
    lg[v][w2] = dot * rn_he[v] * rn_st[w2] / TEMP;
    __syncthreads();
    if (t == 0) {
        float l1 = 0.0f, l2 = 0.0f;
        for (int i = 0; i < VV; ++i) {
            float mx = -1e30f;
            for (int j = 0; j < VV; ++j) mx = fmaxf(mx, lg[i][j]);
            float se = 0.0f;
            for (int j = 0; j < VV; ++j) se += expf(lg[i][j] - mx);
            l1 += lg[i][i] - (mx + logf(se));
            float mx2 = -1e30f;
            for (int j = 0; j < VV; ++j) mx2 = fmaxf(mx2, lg[j][i]);
            float se2 = 0.0f;
            for (int j = 0; j < VV; ++j) se2 += expf(lg[j][i] - mx2);
            l2 += lg[i][i] - (mx2 + logf(se2));
        }
        out[0] = 0.5f * (-(l1 / (float)VV) - (l2 / (float)VV));
    }
}

// ---------------- launch ----------------
extern "C" void kernel_launch(void* const* d_in, const int* in_sizes, int n_in,
                              void* d_out, int out_size, void* d_ws, size_t ws_size,
                              hipStream_t stream) {
    const float* F    = (const float*)d_in[0];
    const float* T    = (const float*)d_in[1];
    const float* E    = (const float*)d_in[3];
    const float* S    = (const float*)d_in[4];
    const float* W_he = (const float*)d_in[5];
    const float* W_st = (const float*)d_in[6];
    float* out = (float*)d_out;

    size_t off = 0;
    auto take = [&](size_t bytes) -> void* {
        void* p = (char*)d_ws + off;
        off += (bytes + 255) & ~(size_t)255;
        return p;
    };
    ushort_t* Fs    = (ushort_t*)take((size_t)NN * 2 * HE_DIM * 2);   // 33.5 MB
    ushort_t* Es    = (ushort_t*)take((size_t)MM * 2 * ST_DIM * 2);   // 4.2 MB
    ushort_t* Whes  = (ushort_t*)take((size_t)D_OUT * 2 * HE_DIM * 2);
    ushort_t* Wsts  = (ushort_t*)take((size_t)D_OUT * 2 * ST_DIM * 2);
    float* Xw_he    = (float*)take((size_t)NN * D_OUT * 4);           // 8 MB
    float* Xw_st    = (float*)take((size_t)MM * D_OUT * 4);           // 2 MB
    float* rnF      = (float*)take((size_t)NN * 4);
    float* rnE      = (float*)take((size_t)MM * 4);
    float* centers  = (float*)take((size_t)VV * 2 * 4);
    int*   mask     = (int*)  take((size_t)VV * MM * 4);
    int*   maskcnt  = (int*)  take((size_t)VV * 4);
    float* he_sim   = (float*)take((size_t)VV * PP * PP * 4);         // 32 MB
    float* st_sim   = (float*)take((size_t)MM * MM * 4);              // 16 MB
    int*   he_idx   = (int*)  take((size_t)NN * K_HG * 4);
    int*   st_idx   = (int*)  take((size_t)VV * MM * K_HG * 4);
    float* he_dv    = (float*)take((size_t)NN * 4);
    float* st_dv    = (float*)take((size_t)VV * MM * 4);
    float* he_acc   = (float*)take((size_t)NN * D_OUT * 4);           // 8 MB
    float* st_acc   = (float*)take((size_t)VV * MM * D_OUT * 4);      // 16 MB
    float* z_he     = (float*)take((size_t)VV * D_OUT * 4);
    float* z_st     = (float*)take((size_t)VV * D_OUT * 4);
    const int he_nchunks = PP / POOL_CHUNK;
    const int st_nchunks = MM / POOL_CHUNK;
    float* he_part = (float*)take((size_t)VV * he_nchunks * D_OUT * 4);
    float* st_part = (float*)take((size_t)VV * st_nchunks * D_OUT * 4);

    // split f32 -> hi/lo bf16
    split_kernel<<<2048, 256, 0, stream>>>(F, Fs, (long)NN * HE_DIM, HE_DIM);
    split_kernel<<<1024, 256, 0, stream>>>(E, Es, (long)MM * ST_DIM, ST_DIM);
    split_kernel<<<256, 256, 0, stream>>>(W_he, Whes, (long)D_OUT * HE_DIM, HE_DIM);
    split_kernel<<<128, 256, 0, stream>>>(W_st, Wsts, (long)D_OUT * ST_DIM, ST_DIM);

    // norms + geometry
    rownorm_kernel<<<NN, 256, 0, stream>>>(F, rnF, HE_DIM);
    rownorm_kernel<<<MM, 256, 0, stream>>>(E, rnE, ST_DIM);
    centers_kernel<<<VV, 256, 0, stream>>>(T, centers);
    hipMemsetAsync(maskcnt, 0, VV * 4, stream);
    mask_kernel<<<(VV * MM + 255) / 256, 256, 0, stream>>>(centers, S, mask, maskcnt);

    // all four GEMMs (2 Grams sym + 2 projections) in ONE grouped launch
    gemm_grouped<<<NB_ALL, 256, 0, stream>>>(Fs, Es, Whes, Wsts,
                                             he_sim, st_sim, Xw_he, Xw_st,
                                             rnF, rnE);

    // top-5
    topk_kernel<<<NN, 64, 0, stream>>>(he_sim, (long)PP * PP, PP, nullptr, 0, he_idx, PP);
    topk_kernel<<<VV * MM, 64, 0, stream>>>(st_sim, 0, MM, mask, MM, st_idx, MM);

    // degrees
    hipMemsetAsync(he_dv, 0, (size_t)NN * 4, stream);
    hipMemsetAsync(st_dv, 0, (size_t)VV * MM * 4, stream);
    dv_kernel<<<(NN * K_HG + 255) / 256, 256, 0, stream>>>(he_idx, he_dv, NN, PP);
    dv_kernel<<<(VV * MM * K_HG + 255) / 256, 256, 0, stream>>>(st_idx, st_dv, VV * MM, MM);

    // conv: edge sums + scatter
    hipMemsetAsync(he_acc, 0, (size_t)NN * D_OUT * 4, stream);
    hipMemsetAsync(st_acc, 0, (size_t)VV * MM * D_OUT * 4, stream);
    edge_kernel<<<NN, 256, 0, stream>>>(he_idx, Xw_he, he_dv, he_acc, PP, PP);
    edge_kernel<<<VV * MM, 256, 0, stream>>>(st_idx, Xw_st, st_dv, st_acc, MM, 0);

    // gelu + pool
    pool_partial_kernel<<<VV * he_nchunks, 256, 0, stream>>>(he_acc, he_dv, nullptr, he_part, PP, he_nchunks);
    pool_partial_kernel<<<VV * st_nchunks, 256, 0, stream>>>(st_acc, st_dv, mask, st_part, MM, st_nchunks);
    pool_reduce_kernel<<<VV, 256, 0, stream>>>(he_part, nullptr, z_he, he_nchunks, PP);
    pool_reduce_kernel<<<VV, 256, 0, stream>>>(st_part, maskcnt, z_st, st_nchunks, MM);

    // loss
    final_kernel<<<1, 64, 0, stream>>>(z_he, z_st, out);
}

// Round 5
// 364.916 us; speedup vs baseline: 3.1249x; 1.0011x over previous
//
#include <hip/hip_runtime.h>
#include <hip/hip_bf16.h>
#include <math.h>

// ---------------- problem constants ----------------
#define NN      8192
#define VV      8
#define PP      1024      // N / V
#define MM      2048
#define HE_DIM  1024
#define ST_DIM  512
#define D_OUT   256
#define K_HG    5
#define RADIUS  150.0f
#define TEMP    0.07f
#define EPSF    1e-12f

#define POOL_CHUNK 16

// grouped-GEMM block ranges
#define HE_TRI   36                 // 8x8 upper triangle
#define ST_TRI   136                // 16x16 upper triangle
#define NB_HE    (VV * HE_TRI)      // 288
#define NB_ST    ST_TRI             // 136
#define NB_PH    ((NN / 128) * (D_OUT / 128))   // 128
#define NB_PS    ((MM / 128) * (D_OUT / 128))   // 32
#define NB_ALL   (NB_HE + NB_ST + NB_PH + NB_PS) // 584  (= 8 * 73, swizzle-exact)

typedef __bf16 bf16x8 __attribute__((ext_vector_type(8)));
typedef float  f32x4  __attribute__((ext_vector_type(4)));
typedef unsigned short ushort_t;

typedef __attribute__((address_space(1))) void gvoid;
typedef __attribute__((address_space(3))) void svoid;
#define GLOAD16(g, l) __builtin_amdgcn_global_load_lds((gvoid*)(g), (svoid*)(l), 16, 0, 0)

// ---------------- f32 -> (hi,lo) bf16 split:  Y[r][k]=hi, Y[r][K+k]=lo ----------------
__global__ __launch_bounds__(256) void split_kernel(const float* __restrict__ X,
                                                    ushort_t* __restrict__ Y,
                                                    long total, int K) {
    long n4 = total >> 2;
    for (long i4 = (long)blockIdx.x * 256 + threadIdx.x; i4 < n4;
         i4 += (long)gridDim.x * 256) {
        float4 x = reinterpret_cast<const float4*>(X)[i4];
        long e0 = i4 << 2;
        long r = e0 / K;
        int  k = (int)(e0 - r * (long)K);
        float xs[4] = {x.x, x.y, x.z, x.w};
        ushort_t hs[4], ls[4];
        #pragma unroll
        for (int j = 0; j < 4; ++j) {
            unsigned int b  = __float_as_uint(xs[j]);
            unsigned int hu = (b + 0x7fffu + ((b >> 16) & 1u)) >> 16;   // RNE bf16
            hs[j] = (ushort_t)hu;
            float hf = __uint_as_float(hu << 16);
            float l  = xs[j] - hf;                                       // exact
            unsigned int lb = __float_as_uint(l);
            unsigned int lu = (lb + 0x7fffu + ((lb >> 16) & 1u)) >> 16;
            ls[j] = (ushort_t)lu;
        }
        ushort_t* rowp = Y + r * 2L * K;
        *reinterpret_cast<ushort4*>(rowp + k)     = make_ushort4(hs[0], hs[1], hs[2], hs[3]);
        *reinterpret_cast<ushort4*>(rowp + K + k) = make_ushort4(ls[0], ls[1], ls[2], ls[3]);
    }
}

// ---------------- row L2 norm reciprocal (from original f32) ----------------
__global__ __launch_bounds__(256) void rownorm_kernel(const float* __restrict__ A,
                                                      float* __restrict__ rn, int K) {
    int row = blockIdx.x;
    const float* a = A + (long)row * K;
    float s = 0.0f;
    for (int j = threadIdx.x; j < K; j += 256) { float x = a[j]; s += x * x; }
    __shared__ float red[256];
    red[threadIdx.x] = s; __syncthreads();
    for (int o = 128; o > 0; o >>= 1) {
        if (threadIdx.x < o) red[threadIdx.x] += red[threadIdx.x + o];
        __syncthreads();
    }
    if (threadIdx.x == 0) rn[row] = 1.0f / fmaxf(sqrtf(red[0]), EPSF);
}

// ---------------- region centroids ----------------
__global__ __launch_bounds__(256) void centers_kernel(const float* __restrict__ T,
                                                      float* __restrict__ centers) {
    int v = blockIdx.x;
    float sx = 0.0f, sy = 0.0f;
    for (int i = threadIdx.x; i < PP; i += 256) {
        sx += T[(long)(v * PP + i) * 2 + 0];
        sy += T[(long)(v * PP + i) * 2 + 1];
    }
    __shared__ float rx[256], ry[256];
    rx[threadIdx.x] = sx; ry[threadIdx.x] = sy; __syncthreads();
    for (int o = 128; o > 0; o >>= 1) {
        if (threadIdx.x < o) { rx[threadIdx.x] += rx[threadIdx.x + o]; ry[threadIdx.x] += ry[threadIdx.x + o]; }
        __syncthreads();
    }
    if (threadIdx.x == 0) {
        centers[v * 2 + 0] = rx[0] / (float)PP;
        centers[v * 2 + 1] = ry[0] / (float)PP;
    }
}

// ---------------- radius mask ----------------
__global__ __launch_bounds__(256) void mask_kernel(const float* __restrict__ centers,
                                                   const float* __restrict__ S,
                                                   int* __restrict__ mask,
                                                   int* __restrict__ maskcnt) {
    int t = blockIdx.x * 256 + threadIdx.x;
    if (t >= VV * MM) return;
    int v = t / MM, m = t - v * MM;
    float dx = centers[v * 2 + 0] - S[m * 2 + 0];
    float dy = centers[v * 2 + 1] - S[m * 2 + 1];
    int in = (sqrtf(dx * dx + dy * dy) < RADIUS) ? 1 : 0;
    mask[t] = in;
    if (in) atomicAdd(&maskcnt[v], 1);
}

// ---------------- grouped split-bf16 MFMA GEMM, single-pass fused hi/lo ----------------
// One launch covers: 8x HE Gram (sym), ST Gram (sym), proj_he, proj_st.
// A,B: [rows][2K] bf16 (hi|lo). Per K-step: stage Ahi,Alo,Bhi,Blo (4 tiles),
// fire 3 MFMA products hi*hi + lo*hi + hi*lo into one accumulator.
// Tile 128x128, BK=32, 256 threads (4 waves 2x2), 16x16x32 MFMA, global_load_lds(16B).
__global__ __launch_bounds__(256) void gemm_grouped(
    const ushort_t* __restrict__ Fs, const ushort_t* __restrict__ Es,
    const ushort_t* __restrict__ Whes, const ushort_t* __restrict__ Wsts,
    float* __restrict__ he_sim, float* __restrict__ st_sim,
    float* __restrict__ Xw_he, float* __restrict__ Xw_st,
    const float* __restrict__ rnF, const float* __restrict__ rnE)
{
    // XCD-aware swizzle: 584 = 8 * 73 exactly -> bijective; each XCD gets a
    // contiguous chunk of logical tile space (same-region tiles share L2).
    int id = (blockIdx.x % 8) * (NB_ALL / 8) + blockIdx.x / 8;

    const ushort_t *A, *B; float *C;
    const float *rA = nullptr, *rB = nullptr;
    int K, Nn, bm, bn, sym;
    if (id < NB_HE) {
        int z = id / HE_TRI, t = id - z * HE_TRI;
        int i = 0;
        while (t >= 8 - i) { t -= 8 - i; ++i; }
        bm = i * 128; bn = (i + t) * 128;
        A = B = Fs + (long)z * PP * 2 * HE_DIM;
        C = he_sim + (long)z * PP * PP;
        rA = rB = rnF + z * PP;
        K = HE_DIM; Nn = PP; sym = 1;
    } else if (id < NB_HE + NB_ST) {
        int t = id - NB_HE;
        int i = 0;
        while (t >= 16 - i) { t -= 16 - i; ++i; }
        bm = i * 128; bn = (i + t) * 128;
        A = B = Es; C = st_sim; rA = rB = rnE;
        K = ST_DIM; Nn = MM; sym = 1;
    } else if (id < NB_HE + NB_ST + NB_PH) {
        int t = id - (NB_HE + NB_ST);
        bm = (t >> 1) * 128; bn = (t & 1) * 128;
        A = Fs; B = Whes; C = Xw_he;
        K = HE_DIM; Nn = D_OUT; sym = 0;
    } else {
        int t = id - (NB_HE + NB_ST + NB_PH);
        bm = (t >> 1) * 128; bn = (t & 1) * 128;
        A = Es; B = Wsts; C = Xw_st;
        K = ST_DIM; Nn = D_OUT; sym = 0;
    }

    __shared__ ushort_t AsH[128 * 32];
    __shared__ ushort_t AsL[128 * 32];
    __shared__ ushort_t BsH[128 * 32];
    __shared__ ushort_t BsL[128 * 32];
    const int tid  = threadIdx.x;
    const int lane = tid & 63, wave = tid >> 6;
    const int wr = wave >> 1, wc = wave & 1;
    const int fr = lane & 15, fg = lane >> 4;

    const long lda = 2L * K;
    const int tb0   = wave * 1024 + lane * 16;
    const int srow0 = tb0 >> 6;          // 64 B per 32-elem tile row
    const int scole = (tb0 & 63) >> 1;

    f32x4 acc[4][4] = {};

    for (int kk = 0; kk < K; kk += 32) {
        const ushort_t* ga = A + (long)(bm + srow0) * lda + kk + scole;
        const ushort_t* gb = B + (long)(bn + srow0) * lda + kk + scole;
        GLOAD16(ga,                (char*)AsH + wave * 1024);
        GLOAD16(ga + 64 * lda,     (char*)AsH + wave * 1024 + 4096);
        GLOAD16(ga + K,            (char*)AsL + wave * 1024);
        GLOAD16(ga + K + 64 * lda, (char*)AsL + wave * 1024 + 4096);
        GLOAD16(gb,                (char*)BsH + wave * 1024);
        GLOAD16(gb + 64 * lda,     (char*)BsH + wave * 1024 + 4096);
        GLOAD16(gb + K,            (char*)BsL + wave * 1024);
        GLOAD16(gb + K + 64 * lda, (char*)BsL + wave * 1024 + 4096);
        __syncthreads();
        bf16x8 ah[4], al[4], bh[4], bl[4];
        #pragma unroll
        for (int m = 0; m < 4; ++m) {
            int ro = (wr * 64 + m * 16 + fr) * 32 + fg * 8;
            ah[m] = *reinterpret_cast<const bf16x8*>(AsH + ro);
            al[m] = *reinterpret_cast<const bf16x8*>(AsL + ro);
        }
        #pragma unroll
        for (int n = 0; n < 4; ++n) {
            int ro = (wc * 64 + n * 16 + fr) * 32 + fg * 8;
            bh[n] = *reinterpret_cast<const bf16x8*>(BsH + ro);
            bl[n] = *reinterpret_cast<const bf16x8*>(BsL + ro);
        }
        #pragma unroll
        for (int m = 0; m < 4; ++m)
            #pragma unroll
            for (int n = 0; n < 4; ++n) {
                acc[m][n] = __builtin_amdgcn_mfma_f32_16x16x32_bf16(ah[m], bh[n], acc[m][n], 0, 0, 0);
                acc[m][n] = __builtin_amdgcn_mfma_f32_16x16x32_bf16(al[m], bh[n], acc[m][n], 0, 0, 0);
                acc[m][n] = __builtin_amdgcn_mfma_f32_16x16x32_bf16(ah[m], bl[n], acc[m][n], 0, 0, 0);
            }
        __syncthreads();
    }

    #pragma unroll
    for (int m = 0; m < 4; ++m) {
        #pragma unroll
        for (int r = 0; r < 4; ++r) {
            int row = bm + wr * 64 + m * 16 + fg * 4 + r;
            float ra = rA ? rA[row] : 1.0f;
            #pragma unroll
            for (int n = 0; n < 4; ++n) {
                int col = bn + wc * 64 + n * 16 + fr;
                float rb = rB ? rB[col] : 1.0f;
                float val = acc[m][n][r] * ra * rb;
                C[(long)row * Nn + col] = val;
                if (sym && bn > bm) C[(long)col * Nn + row] = val;
            }
        }
    }
}

// ---------------- top-5 per row (one wave per row, optional column mask) ----------------
__global__ __launch_bounds__(64) void topk_kernel(
    const float* __restrict__ sim, long simStrideZ, int n,
    const int* __restrict__ mask, int maskStrideZ,
    int* __restrict__ outIdx, int rowsPerZ)
{
    int gb = blockIdx.x;
    int z = gb / rowsPerZ;
    int e = gb - z * rowsPerZ;
    int lane = threadIdx.x;
    const int* mk = mask ? (mask + (long)z * maskStrideZ) : nullptr;
    if (mk && mk[e] == 0) {
        if (lane == 0) {
            #pragma unroll
            for (int r = 0; r < K_HG; ++r) outIdx[(long)gb * K_HG + r] = -1;
        }
        return;
    }
    const float* row = sim + (long)z * simStrideZ + (long)e * n;
    float v[K_HG]; int ix[K_HG];
    #pragma unroll
    for (int r = 0; r < K_HG; ++r) { v[r] = -INFINITY; ix[r] = 0x7fffffff; }
    for (int j = lane; j < n; j += 64) {
        if (mk && mk[j] == 0) continue;
        float s = row[j];
        if (s > v[K_HG - 1]) {
            int p = K_HG - 1;
            #pragma unroll
            for (int q = K_HG - 1; q >= 1; --q) {
                if (s > v[q - 1]) { v[q] = v[q - 1]; ix[q] = ix[q - 1]; p = q - 1; }
                else break;
            }
            v[p] = s; ix[p] = j;
        }
    }
    for (int r = 0; r < K_HG; ++r) {
        float bv = v[0]; int bi = ix[0];
        for (int off = 32; off > 0; off >>= 1) {
            float ov = __shfl_xor(bv, off, 64);
            int   oi = __shfl_xor(bi, off, 64);
            if (ov > bv || (ov == bv && oi < bi)) { bv = ov; bi = oi; }
        }
        if (lane == 0) outIdx[(long)gb * K_HG + r] = bi;
        if (v[0] == bv && ix[0] == bi) {
            #pragma unroll
            for (int p = 0; p < K_HG - 1; ++p) { v[p] = v[p + 1]; ix[p] = ix[p + 1]; }
            v[K_HG - 1] = -INFINITY; ix[K_HG - 1] = 0x7fffffff;
        }
    }
}

// ---------------- node membership counts (int) ----------------
__global__ __launch_bounds__(256) void count_kernel(const int* __restrict__ idx,
                                                    int* __restrict__ cnt,
                                                    int totalEdges, int rowsPerZ) {
    int t = blockIdx.x * 256 + threadIdx.x;
    if (t >= totalEdges * K_HG) return;
    int ge = t / K_HG;
    int z = ge / rowsPerZ;
    int m = idx[t];
    if (m < 0 || m >= rowsPerZ) return;
    atomicAdd(&cnt[z * rowsPerZ + m], 1);
}

// ---------------- exclusive prefix scan (single block, 1024 threads) ----------------
template <int ELT>
__global__ __launch_bounds__(1024) void scan_kernel(const int* __restrict__ cnt,
                                                    int* __restrict__ off) {
    int tid = threadIdx.x;
    int base = tid * ELT;
    int loc[ELT];
    int s = 0;
    #pragma unroll
    for (int i = 0; i < ELT; ++i) { loc[i] = s; s += cnt[base + i]; }
    __shared__ int red[1024];
    red[tid] = s; __syncthreads();
    for (int o = 1; o < 1024; o <<= 1) {
        int t = (tid >= o) ? red[tid - o] : 0;
        __syncthreads();
        red[tid] += t;
        __syncthreads();
    }
    int pre = red[tid] - s;   // exclusive prefix of this thread's chunk
    #pragma unroll
    for (int i = 0; i < ELT; ++i) off[base + i] = pre + loc[i];
}

// ---------------- CSR fill: node -> list of edges containing it ----------------
__global__ __launch_bounds__(256) void fill_kernel(const int* __restrict__ idx,
                                                   const int* __restrict__ off,
                                                   int* __restrict__ cur,
                                                   int* __restrict__ inv,
                                                   int totalEdges, int rowsPerZ) {
    int t = blockIdx.x * 256 + threadIdx.x;
    if (t >= totalEdges * K_HG) return;
    int ge = t / K_HG;
    int z = ge / rowsPerZ;
    int m = idx[t];
    if (m < 0 || m >= rowsPerZ) return;
    int g = z * rowsPerZ + m;
    int pos = atomicAdd(&cur[g], 1);
    inv[off[g] + pos] = ge;
}

// ---------------- per-edge value (no atomics):  ev[e] = (1/5) sum_k dv^-1/2 Xw[m_k] ----------------
__global__ __launch_bounds__(256) void edgeval_kernel(
    const int* __restrict__ idx, const float* __restrict__ Xw,
    const int* __restrict__ cnt, float* __restrict__ ev,
    int rowsPerZ, int xwStrideZ)
{
    int ge = blockIdx.x;
    int z = ge / rowsPerZ;
    int d = threadIdx.x;
    int mm[K_HG];
    #pragma unroll
    for (int k = 0; k < K_HG; ++k) mm[k] = idx[(long)ge * K_HG + k];
    if (mm[0] < 0) return;   // unmasked ST edge: row never referenced
    float val = 0.0f;
    #pragma unroll
    for (int k = 0; k < K_HG; ++k) {
        int m = mm[k];
        if (m < 0 || m >= rowsPerZ) continue;
        float w = rsqrtf(fmaxf((float)cnt[z * rowsPerZ + m], EPSF));
        val += w * Xw[(long)(z * xwStrideZ + m) * D_OUT + d];
    }
    ev[(long)ge * D_OUT + d] = val * (1.0f / (float)K_HG);
}

// ---------------- node gather + Dv^-1/2 + GELU + partial pool (fused) ----------------
__global__ __launch_bounds__(256) void pool_gather_kernel(
    const float* __restrict__ ev, const int* __restrict__ off,
    const int* __restrict__ cnt, const int* __restrict__ inv,
    const int* __restrict__ mask, float* __restrict__ partial,
    int rowsPerZ, int nchunks)
{
    int blk = blockIdx.x;
    int z = blk / nchunks, c = blk - z * nchunks;
    int d = threadIdx.x;
    int i0 = c * POOL_CHUNK;
    float s = 0.0f;
    for (int i = 0; i < POOL_CHUNK; ++i) {
        int g = z * rowsPerZ + i0 + i;
        if (mask && mask[g] == 0) continue;
        int cn = cnt[g], c0 = off[g];
        float a = 0.0f;
        for (int e = 0; e < cn; ++e)
            a += ev[(long)inv[c0 + e] * D_OUT + d];
        float w = rsqrtf(fmaxf((float)cn, EPSF));
        float x = w * a;
        s += 0.5f * x * (1.0f + erff(x * 0.70710678118654752f));   // exact GELU
    }
    partial[(long)blk * D_OUT + d] = s;
}

__global__ __launch_bounds__(256) void pool_reduce_kernel(
    const float* __restrict__ partial, const int* __restrict__ maskcnt,
    float* __restrict__ zout, int nchunks, int rowsPerZ)
{
    int z = blockIdx.x, d = threadIdx.x;
    float s = 0.0f;
    for (int c = 0; c < nchunks; ++c)
        s += partial[(long)(z * nchunks + c) * D_OUT + d];
    float denom = maskcnt ? (float)maskcnt[z] : (float)rowsPerZ;
    zout[z * D_OUT + d] = s / denom;
}

// ---------------- final contrastive loss ----------------
__global__ __launch_bounds__(64) void final_kernel(const float* __restrict__ zhe,
                                                   const float* __restrict__ zst,
                                                   float* __restrict__ out) {
    __shared__ float he[VV][D_OUT];
    __shared__ float st[VV][D_OUT];
    __shared__ float lg[VV][VV];
    __shared__ float rn_he[VV], rn_st[VV];
    int t = threadIdx.x;
    for (int i = t; i < VV * D_OUT; i += 64) {
        he[i >> 8][i & 255] = zhe[i];
        st[i >> 8][i & 255] = zst[i];
    }
    __syncthreads();
    if (t < VV) {
        float s = 0.0f;
        for (int d2 = 0; d2 < D_OUT; ++d2) s += he[t][d2] * he[t][d2];
        rn_he[t] = 1.0f / fmaxf(sqrtf(s), EPSF);
    } else if (t < 2 * VV) {
        int v = t - VV; float s = 0.0f;
        for (int d2 = 0; d2 < D_OUT; ++d2) s += st[v][d2] * st[v][d2];
        rn_st[v] = 1.0f / fmaxf(sqrtf(s), EPSF);
    }
    __syncthreads();
    int v = t >> 3, w2 = t & 7;
    float dot = 0.0f;
    for (int d2 = 0; d2 < D_OUT; ++d2) dot += he[v][d2] * st[w2][d2];
    lg[v][w2] = dot * rn_he[v] * rn_st[w2] / TEMP;
    __syncthreads();
    if (t == 0) {
        float l1 = 0.0f, l2 = 0.0f;
        for (int i = 0; i < VV; ++i) {
            float mx = -1e30f;
            for (int j = 0; j < VV; ++j) mx = fmaxf(mx, lg[i][j]);
            float se = 0.0f;
            for (int j = 0; j < VV; ++j) se += expf(lg[i][j] - mx);
            l1 += lg[i][i] - (mx + logf(se));
            float mx2 = -1e30f;
            for (int j = 0; j < VV; ++j) mx2 = fmaxf(mx2, lg[j][i]);
            float se2 = 0.0f;
            for (int j = 0; j < VV; ++j) se2 += expf(lg[j][i] - mx2);
            l2 += lg[i][i] - (mx2 + logf(se2));
        }
        out[0] = 0.5f * (-(l1 / (float)VV) - (l2 / (float)VV));
    }
}

// ---------------- launch ----------------
extern "C" void kernel_launch(void* const* d_in, const int* in_sizes, int n_in,
                              void* d_out, int out_size, void* d_ws, size_t ws_size,
                              hipStream_t stream) {
    const float* F    = (const float*)d_in[0];
    const float* T    = (const float*)d_in[1];
    const float* E    = (const float*)d_in[3];
    const float* S    = (const float*)d_in[4];
    const float* W_he = (const float*)d_in[5];
    const float* W_st = (const float*)d_in[6];
    float* out = (float*)d_out;

    size_t off = 0;
    auto take = [&](size_t bytes) -> void* {
        void* p = (char*)d_ws + off;
        off += (bytes + 255) & ~(size_t)255;
        return p;
    };
    ushort_t* Fs    = (ushort_t*)take((size_t)NN * 2 * HE_DIM * 2);   // 33.5 MB
    ushort_t* Es    = (ushort_t*)take((size_t)MM * 2 * ST_DIM * 2);   // 4.2 MB
    ushort_t* Whes  = (ushort_t*)take((size_t)D_OUT * 2 * HE_DIM * 2);
    ushort_t* Wsts  = (ushort_t*)take((size_t)D_OUT * 2 * ST_DIM * 2);
    float* Xw_he    = (float*)take((size_t)NN * D_OUT * 4);           // 8 MB
    float* Xw_st    = (float*)take((size_t)MM * D_OUT * 4);           // 2 MB
    float* rnF      = (float*)take((size_t)NN * 4);
    float* rnE      = (float*)take((size_t)MM * 4);
    float* centers  = (float*)take((size_t)VV * 2 * 4);
    int*   mask     = (int*)  take((size_t)VV * MM * 4);
    int*   maskcnt  = (int*)  take((size_t)VV * 4);
    float* he_sim   = (float*)take((size_t)VV * PP * PP * 4);         // 32 MB
    float* st_sim   = (float*)take((size_t)MM * MM * 4);              // 16 MB
    int*   he_idx   = (int*)  take((size_t)NN * K_HG * 4);
    int*   st_idx   = (int*)  take((size_t)VV * MM * K_HG * 4);
    // zero-init region: counts + cursors (contiguous takes)
    size_t zero_beg = off;
    int*   he_cnt   = (int*)  take((size_t)NN * 4);
    int*   st_cnt   = (int*)  take((size_t)VV * MM * 4);
    int*   he_cur   = (int*)  take((size_t)NN * 4);
    int*   st_cur   = (int*)  take((size_t)VV * MM * 4);
    size_t zero_end = off;
    int*   he_off   = (int*)  take((size_t)NN * 4);
    int*   st_off   = (int*)  take((size_t)VV * MM * 4);
    int*   he_inv   = (int*)  take((size_t)NN * K_HG * 4);
    int*   st_inv   = (int*)  take((size_t)VV * MM * K_HG * 4);
    float* he_ev    = (float*)take((size_t)NN * D_OUT * 4);           // 8 MB
    float* st_ev    = (float*)take((size_t)VV * MM * D_OUT * 4);      // 16 MB
    float* z_he     = (float*)take((size_t)VV * D_OUT * 4);
    float* z_st     = (float*)take((size_t)VV * D_OUT * 4);
    const int he_nchunks = PP / POOL_CHUNK;   // 64
    const int st_nchunks = MM / POOL_CHUNK;   // 128
    float* he_part = (float*)take((size_t)VV * he_nchunks * D_OUT * 4);
    float* st_part = (float*)take((size_t)VV * st_nchunks * D_OUT * 4);

    // split f32 -> hi/lo bf16
    split_kernel<<<2048, 256, 0, stream>>>(F, Fs, (long)NN * HE_DIM, HE_DIM);
    split_kernel<<<1024, 256, 0, stream>>>(E, Es, (long)MM * ST_DIM, ST_DIM);
    split_kernel<<<256, 256, 0, stream>>>(W_he, Whes, (long)D_OUT * HE_DIM, HE_DIM);
    split_kernel<<<128, 256, 0, stream>>>(W_st, Wsts, (long)D_OUT * ST_DIM, ST_DIM);

    // norms + geometry
    rownorm_kernel<<<NN, 256, 0, stream>>>(F, rnF, HE_DIM);
    rownorm_kernel<<<MM, 256, 0, stream>>>(E, rnE, ST_DIM);
    centers_kernel<<<VV, 256, 0, stream>>>(T, centers);
    hipMemsetAsync(maskcnt, 0, VV * 4, stream);
    hipMemsetAsync((char*)d_ws + zero_beg, 0, zero_end - zero_beg, stream);
    mask_kernel<<<(VV * MM + 255) / 256, 256, 0, stream>>>(centers, S, mask, maskcnt);

    // all four GEMMs (2 Grams sym + 2 projections) in ONE grouped launch
    gemm_grouped<<<NB_ALL, 256, 0, stream>>>(Fs, Es, Whes, Wsts,
                                             he_sim, st_sim, Xw_he, Xw_st,
                                             rnF, rnE);

    // top-5
    topk_kernel<<<NN, 64, 0, stream>>>(he_sim, (long)PP * PP, PP, nullptr, 0, he_idx, PP);
    topk_kernel<<<VV * MM, 64, 0, stream>>>(st_sim, 0, MM, mask, MM, st_idx, MM);

    // node degrees (int) + CSR inversion
    count_kernel<<<(NN * K_HG + 255) / 256, 256, 0, stream>>>(he_idx, he_cnt, NN, PP);
    count_kernel<<<(VV * MM * K_HG + 255) / 256, 256, 0, stream>>>(st_idx, st_cnt, VV * MM, MM);
    scan_kernel<NN / 1024><<<1, 1024, 0, stream>>>(he_cnt, he_off);
    scan_kernel<(VV * MM) / 1024><<<1, 1024, 0, stream>>>(st_cnt, st_off);
    fill_kernel<<<(NN * K_HG + 255) / 256, 256, 0, stream>>>(he_idx, he_off, he_cur, he_inv, NN, PP);
    fill_kernel<<<(VV * MM * K_HG + 255) / 256, 256, 0, stream>>>(st_idx, st_off, st_cur, st_inv, VV * MM, MM);

    // per-edge values (dense write, no atomics)
    edgeval_kernel<<<NN, 256, 0, stream>>>(he_idx, Xw_he, he_cnt, he_ev, PP, PP);
    edgeval_kernel<<<VV * MM, 256, 0, stream>>>(st_idx, Xw_st, st_cnt, st_ev, MM, 0);

    // node gather + gelu + pool (fused partials) then reduce
    pool_gather_kernel<<<VV * he_nchunks, 256, 0, stream>>>(he_ev, he_off, he_cnt, he_inv,
                                                            nullptr, he_part, PP, he_nchunks);
    pool_gather_kernel<<<VV * st_nchunks, 256, 0, stream>>>(st_ev, st_off, st_cnt, st_inv,
                                                            mask, st_part, MM, st_nchunks);
    pool_reduce_kernel<<<VV, 256, 0, stream>>>(he_part, nullptr, z_he, he_nchunks, PP);
    pool_reduce_kernel<<<VV, 256, 0, stream>>>(st_part, maskcnt, z_st, st_nchunks, MM);

    // loss
    final_kernel<<<1, 64, 0, stream>>>(z_he, z_st, out);
}

// Round 6
// 302.951 us; speedup vs baseline: 3.7641x; 1.2045x over previous
//
#include <hip/hip_runtime.h>
#include <hip/hip_bf16.h>
#include <math.h>

// ---------------- problem constants ----------------
#define NN      8192
#define VV      8
#define PP      1024      // N / V
#define MM      2048
#define HE_DIM  1024
#define ST_DIM  512
#define D_OUT   256
#define K_HG    5
#define RADIUS  150.0f
#define TEMP    0.07f
#define EPSF    1e-12f

#define POOL_CHUNK 16
#define HE_NCH  (PP / POOL_CHUNK)   // 64
#define ST_NCH  (MM / POOL_CHUNK)   // 128

// grouped-GEMM block ranges
#define HE_TRI   36                 // 8x8 upper triangle
#define ST_TRI   136                // 16x16 upper triangle
#define NB_HE    (VV * HE_TRI)      // 288
#define NB_ST    ST_TRI             // 136
#define NB_PH    ((NN / 128) * (D_OUT / 128))   // 128
#define NB_PS    ((MM / 128) * (D_OUT / 128))   // 32
#define NB_ALL   (NB_HE + NB_ST + NB_PH + NB_PS) // 584 = 8 * 73

typedef __bf16 bf16x8 __attribute__((ext_vector_type(8)));
typedef float  f32x4  __attribute__((ext_vector_type(4)));
typedef unsigned short ushort_t;

typedef __attribute__((address_space(1))) void gvoid;
typedef __attribute__((address_space(3))) void svoid;
#define GLOAD16(g, l) __builtin_amdgcn_global_load_lds((gvoid*)(g), (svoid*)(l), 16, 0, 0)

// ---------------- fused: f32 -> (hi,lo) bf16 split + row L2 norm ----------------
// grid = NN (F rows) + MM (E rows) + D_OUT (W_he rows) + D_OUT (W_st rows)
__global__ __launch_bounds__(256) void prep_kernel(
    const float* __restrict__ F, const float* __restrict__ E,
    const float* __restrict__ Whe, const float* __restrict__ Wst,
    ushort_t* __restrict__ Fs, ushort_t* __restrict__ Es,
    ushort_t* __restrict__ Whes, ushort_t* __restrict__ Wsts,
    float* __restrict__ rnF, float* __restrict__ rnE)
{
    int b = blockIdx.x;
    const float* src; ushort_t* dst; float* rn; int K; long row;
    if (b < NN)                    { src = F;   dst = Fs;   rn = rnF;    K = HE_DIM; row = b; }
    else if (b < NN + MM)          { src = E;   dst = Es;   rn = rnE;    K = ST_DIM; row = b - NN; }
    else if (b < NN + MM + D_OUT)  { src = Whe; dst = Whes; rn = nullptr; K = HE_DIM; row = b - NN - MM; }
    else                           { src = Wst; dst = Wsts; rn = nullptr; K = ST_DIM; row = b - NN - MM - D_OUT; }
    const float4* srow = (const float4*)(src + row * (long)K);
    ushort_t* drow = dst + row * 2L * K;
    float s = 0.0f;
    for (int j4 = threadIdx.x; j4 < (K >> 2); j4 += 256) {
        float4 x = srow[j4];
        float xs[4] = {x.x, x.y, x.z, x.w};
        ushort_t hs[4], ls[4];
        #pragma unroll
        for (int t = 0; t < 4; ++t) {
            unsigned int bb = __float_as_uint(xs[t]);
            unsigned int hu = (bb + 0x7fffu + ((bb >> 16) & 1u)) >> 16;   // RNE bf16
            hs[t] = (ushort_t)hu;
            float hf = __uint_as_float(hu << 16);
            float l  = xs[t] - hf;                                        // exact
            unsigned int lb = __float_as_uint(l);
            ls[t] = (ushort_t)((lb + 0x7fffu + ((lb >> 16) & 1u)) >> 16);
            s += xs[t] * xs[t];
        }
        *(ushort4*)(drow + j4 * 4)     = make_ushort4(hs[0], hs[1], hs[2], hs[3]);
        *(ushort4*)(drow + K + j4 * 4) = make_ushort4(ls[0], ls[1], ls[2], ls[3]);
    }
    if (rn) {
        __shared__ float red[256];
        red[threadIdx.x] = s; __syncthreads();
        for (int o = 128; o > 0; o >>= 1) {
            if (threadIdx.x < o) red[threadIdx.x] += red[threadIdx.x + o];
            __syncthreads();
        }
        if (threadIdx.x == 0) rn[row] = 1.0f / fmaxf(sqrtf(red[0]), EPSF);
    }
}

// ---------------- region centroids (+ maskcnt zero) ----------------
__global__ __launch_bounds__(256) void centers_kernel(const float* __restrict__ T,
                                                      float* __restrict__ centers,
                                                      int* __restrict__ maskcnt) {
    int v = blockIdx.x;
    float sx = 0.0f, sy = 0.0f;
    for (int i = threadIdx.x; i < PP; i += 256) {
        sx += T[(long)(v * PP + i) * 2 + 0];
        sy += T[(long)(v * PP + i) * 2 + 1];
    }
    __shared__ float rx[256], ry[256];
    rx[threadIdx.x] = sx; ry[threadIdx.x] = sy; __syncthreads();
    for (int o = 128; o > 0; o >>= 1) {
        if (threadIdx.x < o) { rx[threadIdx.x] += rx[threadIdx.x + o]; ry[threadIdx.x] += ry[threadIdx.x + o]; }
        __syncthreads();
    }
    if (threadIdx.x == 0) {
        centers[v * 2 + 0] = rx[0] / (float)PP;
        centers[v * 2 + 1] = ry[0] / (float)PP;
        maskcnt[v] = 0;
    }
}

// ---------------- radius mask ----------------
__global__ __launch_bounds__(256) void mask_kernel(const float* __restrict__ centers,
                                                   const float* __restrict__ S,
                                                   int* __restrict__ mask,
                                                   int* __restrict__ maskcnt) {
    int t = blockIdx.x * 256 + threadIdx.x;
    if (t >= VV * MM) return;
    int v = t / MM, m = t - v * MM;
    float dx = centers[v * 2 + 0] - S[m * 2 + 0];
    float dy = centers[v * 2 + 1] - S[m * 2 + 1];
    int in = (sqrtf(dx * dx + dy * dy) < RADIUS) ? 1 : 0;
    mask[t] = in;
    if (in) atomicAdd(&maskcnt[v], 1);
}

// ---------------- grouped split-bf16 MFMA GEMM, double-buffered prefetch ----------------
// Per K-step: STAGE next tile (8x global_load_lds into buf^1) BEFORE ds_read+MFMA
// of buf; ONE vmcnt(0)+barrier per step (minimum 2-phase recipe).
__global__ __launch_bounds__(256) void gemm_grouped(
    const ushort_t* __restrict__ Fs, const ushort_t* __restrict__ Es,
    const ushort_t* __restrict__ Whes, const ushort_t* __restrict__ Wsts,
    float* __restrict__ he_sim, float* __restrict__ st_sim,
    float* __restrict__ Xw_he, float* __restrict__ Xw_st,
    const float* __restrict__ rnF, const float* __restrict__ rnE)
{
    // Balanced XCD map: XCD k owns region k's 36 HE tiles (its Fs panel ~4MB = one L2)
    // plus a round-robin 37-slice of the ST/proj tiles (uniform work per XCD).
    int bid = blockIdx.x;
    int xcd = bid & 7, j = bid >> 3;    // 584 = 8*73, bijective
    int id = (j < HE_TRI) ? (xcd * HE_TRI + j)
                          : (NB_HE + (j - HE_TRI) * 8 + xcd);

    const ushort_t *A, *B; float *C;
    const float *rA = nullptr, *rB = nullptr;
    int K, Nn, bm, bn, sym;
    if (id < NB_HE) {
        int z = id / HE_TRI, t = id - z * HE_TRI;
        int i = 0;
        while (t >= 8 - i) { t -= 8 - i; ++i; }
        bm = i * 128; bn = (i + t) * 128;
        A = B = Fs + (long)z * PP * 2 * HE_DIM;
        C = he_sim + (long)z * PP * PP;
        rA = rB = rnF + z * PP;
        K = HE_DIM; Nn = PP; sym = 1;
    } else if (id < NB_HE + NB_ST) {
        int t = id - NB_HE;
        int i = 0;
        while (t >= 16 - i) { t -= 16 - i; ++i; }
        bm = i * 128; bn = (i + t) * 128;
        A = B = Es; C = st_sim; rA = rB = rnE;
        K = ST_DIM; Nn = MM; sym = 1;
    } else if (id < NB_HE + NB_ST + NB_PH) {
        int t = id - (NB_HE + NB_ST);
        bm = (t >> 1) * 128; bn = (t & 1) * 128;
        A = Fs; B = Whes; C = Xw_he;
        K = HE_DIM; Nn = D_OUT; sym = 0;
    } else {
        int t = id - (NB_HE + NB_ST + NB_PH);
        bm = (t >> 1) * 128; bn = (t & 1) * 128;
        A = Es; B = Wsts; C = Xw_st;
        K = ST_DIM; Nn = D_OUT; sym = 0;
    }

    // 2 buffers x 4 tiles (AH, AL, BH, BL) x 8 KB = 64 KB
    __shared__ ushort_t sm[2][4][4096];
    const int tid  = threadIdx.x;
    const int lane = tid & 63, wave = tid >> 6;
    const int wr = wave >> 1, wc = wave & 1;
    const int fr = lane & 15, fg = lane >> 4;

    const long lda = 2L * K;
    const int tb0   = wave * 1024 + lane * 16;
    const int srow0 = tb0 >> 6;          // 64 B per 32-elem tile row
    const int scole = (tb0 & 63) >> 1;

    auto STAGE = [&](int kk, int b) {
        const ushort_t* ga = A + (long)(bm + srow0) * lda + kk + scole;
        const ushort_t* gb = B + (long)(bn + srow0) * lda + kk + scole;
        char* AH = (char*)&sm[b][0][0] + wave * 1024;
        char* AL = (char*)&sm[b][1][0] + wave * 1024;
        char* BH = (char*)&sm[b][2][0] + wave * 1024;
        char* BL = (char*)&sm[b][3][0] + wave * 1024;
        GLOAD16(ga,                AH); GLOAD16(ga + 64 * lda,     AH + 4096);
        GLOAD16(ga + K,            AL); GLOAD16(ga + K + 64 * lda, AL + 4096);
        GLOAD16(gb,                BH); GLOAD16(gb + 64 * lda,     BH + 4096);
        GLOAD16(gb + K,            BL); GLOAD16(gb + K + 64 * lda, BL + 4096);
    };

    f32x4 acc[4][4] = {};
    STAGE(0, 0);
    __syncthreads();
    int buf = 0;
    for (int kk = 0; kk < K; kk += 32) {
        if (kk + 32 < K) STAGE(kk + 32, buf ^ 1);   // prefetch overlaps compute below
        bf16x8 ah[4], al[4], bh[4], bl[4];
        #pragma unroll
        for (int m = 0; m < 4; ++m) {
            int ro = (wr * 64 + m * 16 + fr) * 32 + fg * 8;
            ah[m] = *(const bf16x8*)&sm[buf][0][ro];
            al[m] = *(const bf16x8*)&sm[buf][1][ro];
        }
        #pragma unroll
        for (int n = 0; n < 4; ++n) {
            int ro = (wc * 64 + n * 16 + fr) * 32 + fg * 8;
            bh[n] = *(const bf16x8*)&sm[buf][2][ro];
            bl[n] = *(const bf16x8*)&sm[buf][3][ro];
        }
        #pragma unroll
        for (int m = 0; m < 4; ++m)
            #pragma unroll
            for (int n = 0; n < 4; ++n) {
                acc[m][n] = __builtin_amdgcn_mfma_f32_16x16x32_bf16(ah[m], bh[n], acc[m][n], 0, 0, 0);
                acc[m][n] = __builtin_amdgcn_mfma_f32_16x16x32_bf16(al[m], bh[n], acc[m][n], 0, 0, 0);
                acc[m][n] = __builtin_amdgcn_mfma_f32_16x16x32_bf16(ah[m], bl[n], acc[m][n], 0, 0, 0);
            }
        __syncthreads();   // drains vmcnt (prefetch) + lgkm; one barrier per K-step
        buf ^= 1;
    }

    #pragma unroll
    for (int m = 0; m < 4; ++m) {
        #pragma unroll
        for (int r = 0; r < 4; ++r) {
            int row = bm + wr * 64 + m * 16 + fg * 4 + r;
            float ra = rA ? rA[row] : 1.0f;
            #pragma unroll
            for (int n = 0; n < 4; ++n) {
                int col = bn + wc * 64 + n * 16 + fr;
                float rb = rB ? rB[col] : 1.0f;
                float val = acc[m][n][r] * ra * rb;
                C[(long)row * Nn + col] = val;
                if (sym && bn > bm) C[(long)col * Nn + row] = val;
            }
        }
    }
}

// ---------------- merged top-5 per row + degree counts ----------------
// grid = NN (HE rows) + VV*MM (ST rows); one wave per row
__global__ __launch_bounds__(64) void topk_kernel(
    const float* __restrict__ he_sim, const float* __restrict__ st_sim,
    const int* __restrict__ mask,
    int* __restrict__ he_idx, int* __restrict__ st_idx,
    int* __restrict__ he_cnt, int* __restrict__ st_cnt)
{
    int gb = blockIdx.x;
    const float* row; const int* mk = nullptr; int* outIdx; int* cntp; int n;
    if (gb < NN) {
        int z = gb >> 10, e = gb & (PP - 1);
        row = he_sim + (long)z * PP * PP + (long)e * PP;
        outIdx = he_idx + (long)gb * K_HG;
        cntp = he_cnt + z * PP;
        n = PP;
    } else {
        int g2 = gb - NN;
        int z = g2 >> 11, e = g2 & (MM - 1);
        mk = mask + (long)z * MM;
        row = st_sim + (long)e * MM;
        outIdx = st_idx + (long)g2 * K_HG;
        cntp = st_cnt + z * MM;
        n = MM;
        if (mk[e] == 0) {
            if (threadIdx.x == 0) {
                #pragma unroll
                for (int r = 0; r < K_HG; ++r) outIdx[r] = -1;
            }
            return;
        }
    }
    int lane = threadIdx.x;
    float v[K_HG]; int ix[K_HG];
    #pragma unroll
    for (int r = 0; r < K_HG; ++r) { v[r] = -INFINITY; ix[r] = 0x7fffffff; }
    for (int jj = lane; jj < n; jj += 64) {
        if (mk && mk[jj] == 0) continue;
        float s = row[jj];
        if (s > v[K_HG - 1]) {
            int p = K_HG - 1;
            #pragma unroll
            for (int q = K_HG - 1; q >= 1; --q) {
                if (s > v[q - 1]) { v[q] = v[q - 1]; ix[q] = ix[q - 1]; p = q - 1; }
                else break;
            }
            v[p] = s; ix[p] = jj;
        }
    }
    int sel[K_HG];
    #pragma unroll
    for (int r = 0; r < K_HG; ++r) {
        float bv = v[0]; int bi = ix[0];
        for (int o = 32; o > 0; o >>= 1) {
            float ov = __shfl_xor(bv, o, 64);
            int   oi = __shfl_xor(bi, o, 64);
            if (ov > bv || (ov == bv && oi < bi)) { bv = ov; bi = oi; }
        }
        if (lane == 0) { outIdx[r] = bi; sel[r] = bi; }
        if (v[0] == bv && ix[0] == bi) {
            #pragma unroll
            for (int p = 0; p < K_HG - 1; ++p) { v[p] = v[p + 1]; ix[p] = ix[p + 1]; }
            v[K_HG - 1] = -INFINITY; ix[K_HG - 1] = 0x7fffffff;
        }
    }
    if (lane == 0) {
        #pragma unroll
        for (int r = 0; r < K_HG; ++r) atomicAdd(&cntp[sel[r]], 1);
    }
}

// ---------------- merged exclusive prefix scans (2 blocks) ----------------
template <int ELT>
__device__ void scan_impl(const int* __restrict__ cnt, int* __restrict__ off) {
    int tid = threadIdx.x;
    int base = tid * ELT;
    int loc[ELT]; int s = 0;
    #pragma unroll
    for (int i = 0; i < ELT; ++i) { loc[i] = s; s += cnt[base + i]; }
    __shared__ int red[1024];
    red[tid] = s; __syncthreads();
    for (int o = 1; o < 1024; o <<= 1) {
        int t = (tid >= o) ? red[tid - o] : 0;
        __syncthreads();
        red[tid] += t;
        __syncthreads();
    }
    int pre = red[tid] - s;
    #pragma unroll
    for (int i = 0; i < ELT; ++i) off[base + i] = pre + loc[i];
}

__global__ __launch_bounds__(1024) void scan_kernel(
    const int* __restrict__ he_cnt, int* __restrict__ he_off,
    const int* __restrict__ st_cnt, int* __restrict__ st_off) {
    if (blockIdx.x == 0) scan_impl<NN / 1024>(he_cnt, he_off);
    else                 scan_impl<(VV * MM) / 1024>(st_cnt, st_off);
}

// ---------------- merged per-edge value + CSR fill ----------------
// grid = NN + VV*MM; block = edge; 256 threads over D_OUT; threads 0..4 do fill
__global__ __launch_bounds__(256) void edge_kernel(
    const int* __restrict__ he_idx, const int* __restrict__ st_idx,
    const float* __restrict__ Xw_he, const float* __restrict__ Xw_st,
    const int* __restrict__ he_cnt, const int* __restrict__ st_cnt,
    const int* __restrict__ he_off, const int* __restrict__ st_off,
    int* __restrict__ he_cur, int* __restrict__ st_cur,
    int* __restrict__ he_inv, int* __restrict__ st_inv,
    float* __restrict__ he_ev, float* __restrict__ st_ev)
{
    int b = blockIdx.x;
    const int *idx, *cnt, *off; const float* Xw;
    int *cur, *inv; float* ev;
    int ge, gbase, rowsPerZ; long xwBase;
    if (b < NN) {
        ge = b; int z = ge >> 10;
        idx = he_idx; Xw = Xw_he; cnt = he_cnt; off = he_off;
        cur = he_cur; inv = he_inv; ev = he_ev;
        rowsPerZ = PP; gbase = z * PP; xwBase = (long)z * PP;
    } else {
        ge = b - NN; int z = ge >> 11;
        idx = st_idx; Xw = Xw_st; cnt = st_cnt; off = st_off;
        cur = st_cur; inv = st_inv; ev = st_ev;
        rowsPerZ = MM; gbase = z * MM; xwBase = 0;
    }
    int mm[K_HG];
    #pragma unroll
    for (int k = 0; k < K_HG; ++k) mm[k] = idx[(long)ge * K_HG + k];
    if (mm[0] < 0) return;   // masked-out ST edge: never referenced
    int d = threadIdx.x;
    float val = 0.0f;
    #pragma unroll
    for (int k = 0; k < K_HG; ++k) {
        int m = mm[k];
        if (m < 0 || m >= rowsPerZ) continue;
        float w = rsqrtf(fmaxf((float)cnt[gbase + m], EPSF));
        val += w * Xw[(xwBase + m) * D_OUT + d];
    }
    ev[(long)ge * D_OUT + d] = val * (1.0f / (float)K_HG);
    if (d < K_HG) {
        int m = mm[d];
        if (m >= 0 && m < rowsPerZ) {
            int g = gbase + m;
            int pos = atomicAdd(&cur[g], 1);
            inv[off[g] + pos] = ge;
        }
    }
}

// ---------------- merged node gather + Dv^-1/2 + GELU + partial pool ----------------
__global__ __launch_bounds__(256) void pool_gather_kernel(
    const float* __restrict__ he_ev, const float* __restrict__ st_ev,
    const int* __restrict__ he_off, const int* __restrict__ st_off,
    const int* __restrict__ he_cnt, const int* __restrict__ st_cnt,
    const int* __restrict__ he_inv, const int* __restrict__ st_inv,
    const int* __restrict__ mask,
    float* __restrict__ he_part, float* __restrict__ st_part)
{
    int blk = blockIdx.x;
    const float* ev; const int *off, *cnt, *inv, *msk = nullptr;
    float* partial; int gbase, i0;
    if (blk < VV * HE_NCH) {
        int z = blk >> 6, c = blk & (HE_NCH - 1);
        ev = he_ev; off = he_off; cnt = he_cnt; inv = he_inv;
        partial = he_part + (long)blk * D_OUT;
        gbase = z * PP; i0 = c * POOL_CHUNK;
    } else {
        int b2 = blk - VV * HE_NCH;
        int z = b2 >> 7, c = b2 & (ST_NCH - 1);
        ev = st_ev; off = st_off; cnt = st_cnt; inv = st_inv;
        msk = mask;
        partial = st_part + (long)b2 * D_OUT;
        gbase = z * MM; i0 = c * POOL_CHUNK;
    }
    int d = threadIdx.x;
    float s = 0.0f;
    for (int i = 0; i < POOL_CHUNK; ++i) {
        int g = gbase + i0 + i;
        if (msk && msk[g] == 0) continue;
        int cn = cnt[g], c0 = off[g];
        float a = 0.0f;
        for (int e = 0; e < cn; ++e)
            a += ev[(long)inv[c0 + e] * D_OUT + d];
        float w = rsqrtf(fmaxf((float)cn, EPSF));
        float x = w * a;
        s += 0.5f * x * (1.0f + erff(x * 0.70710678118654752f));   // exact GELU
    }
    partial[d] = s;
}

// ---------------- final: partial-reduce + l2norm + contrastive loss ----------------
__global__ __launch_bounds__(256) void final_kernel(
    const float* __restrict__ he_part, const float* __restrict__ st_part,
    const int* __restrict__ maskcnt, float* __restrict__ out)
{
    __shared__ float he[VV][D_OUT];
    __shared__ float st[VV][D_OUT];
    __shared__ float lg[VV][VV];
    __shared__ float rn_he[VV], rn_st[VV];
    int d = threadIdx.x;
    for (int v = 0; v < VV; ++v) {
        float s = 0.0f;
        for (int c = 0; c < HE_NCH; ++c) s += he_part[(long)(v * HE_NCH + c) * D_OUT + d];
        he[v][d] = s / (float)PP;
        float s2 = 0.0f;
        for (int c = 0; c < ST_NCH; ++c) s2 += st_part[(long)(v * ST_NCH + c) * D_OUT + d];
        st[v][d] = s2 / (float)maskcnt[v];
    }
    __syncthreads();
    int t = threadIdx.x;
    if (t < VV) {
        float s = 0.0f;
        for (int d2 = 0; d2 < D_OUT; ++d2) s += he[t][d2] * he[t][d2];
        rn_he[t] = 1.0f / fmaxf(sqrtf(s), EPSF);
    } else if (t < 2 * VV) {
        int v = t - VV; float s = 0.0f;
        for (int d2 = 0; d2 < D_OUT; ++d2) s += st[v][d2] * st[v][d2];
        rn_st[v] = 1.0f / fmaxf(sqrtf(s), EPSF);
    }
    __syncthreads();
    if (t < VV * VV) {
        int v = t >> 3, w2 = t & 7;
        float dot = 0.0f;
        for (int d2 = 0; d2 < D_OUT; ++d2) dot += he[v][d2] * st[w2][d2];
        lg[v][w2] = dot * rn_he[v] * rn_st[w2] / TEMP;
    }
    __syncthreads();
    if (t == 0) {
        float l1 = 0.0f, l2 = 0.0f;
        for (int i = 0; i < VV; ++i) {
            float mx = -1e30f;
            for (int jj = 0; jj < VV; ++jj) mx = fmaxf(mx, lg[i][jj]);
            float se = 0.0f;
            for (int jj = 0; jj < VV; ++jj) se += expf(lg[i][jj] - mx);
            l1 += lg[i][i] - (mx + logf(se));
            float mx2 = -1e30f;
            for (int jj = 0; jj < VV; ++jj) mx2 = fmaxf(mx2, lg[jj][i]);
            float se2 = 0.0f;
            for (int jj = 0; jj < VV; ++jj) se2 += expf(lg[jj][i] - mx2);
            l2 += lg[i][i] - (mx2 + logf(se2));
        }
        out[0] = 0.5f * (-(l1 / (float)VV) - (l2 / (float)VV));
    }
}

// ---------------- launch ----------------
extern "C" void kernel_launch(void* const* d_in, const int* in_sizes, int n_in,
                              void* d_out, int out_size, void* d_ws, size_t ws_size,
                              hipStream_t stream) {
    const float* F    = (const float*)d_in[0];
    const float* T    = (const float*)d_in[1];
    const float* E    = (const float*)d_in[3];
    const float* S    = (const float*)d_in[4];
    const float* W_he = (const float*)d_in[5];
    const float* W_st = (const float*)d_in[6];
    float* out = (float*)d_out;

    size_t off = 0;
    auto take = [&](size_t bytes) -> void* {
        void* p = (char*)d_ws + off;
        off += (bytes + 255) & ~(size_t)255;
        return p;
    };
    ushort_t* Fs    = (ushort_t*)take((size_t)NN * 2 * HE_DIM * 2);   // 33.5 MB
    ushort_t* Es    = (ushort_t*)take((size_t)MM * 2 * ST_DIM * 2);   // 4.2 MB
    ushort_t* Whes  = (ushort_t*)take((size_t)D_OUT * 2 * HE_DIM * 2);
    ushort_t* Wsts  = (ushort_t*)take((size_t)D_OUT * 2 * ST_DIM * 2);
    float* Xw_he    = (float*)take((size_t)NN * D_OUT * 4);           // 8 MB
    float* Xw_st    = (float*)take((size_t)MM * D_OUT * 4);           // 2 MB
    float* rnF      = (float*)take((size_t)NN * 4);
    float* rnE      = (float*)take((size_t)MM * 4);
    float* centers  = (float*)take((size_t)VV * 2 * 4);
    int*   mask     = (int*)  take((size_t)VV * MM * 4);
    int*   maskcnt  = (int*)  take((size_t)VV * 4);
    float* he_sim   = (float*)take((size_t)VV * PP * PP * 4);         // 32 MB
    float* st_sim   = (float*)take((size_t)MM * MM * 4);              // 16 MB
    int*   he_idx   = (int*)  take((size_t)NN * K_HG * 4);
    int*   st_idx   = (int*)  take((size_t)VV * MM * K_HG * 4);
    // zero-init region (one memset): counts + cursors
    size_t zero_beg = off;
    int*   he_cnt   = (int*)  take((size_t)NN * 4);
    int*   st_cnt   = (int*)  take((size_t)VV * MM * 4);
    int*   he_cur   = (int*)  take((size_t)NN * 4);
    int*   st_cur   = (int*)  take((size_t)VV * MM * 4);
    size_t zero_end = off;
    int*   he_off   = (int*)  take((size_t)NN * 4);
    int*   st_off   = (int*)  take((size_t)VV * MM * 4);
    int*   he_inv   = (int*)  take((size_t)NN * K_HG * 4);
    int*   st_inv   = (int*)  take((size_t)VV * MM * K_HG * 4);
    float* he_ev    = (float*)take((size_t)NN * D_OUT * 4);           // 8 MB
    float* st_ev    = (float*)take((size_t)VV * MM * D_OUT * 4);      // 16 MB
    float* he_part  = (float*)take((size_t)VV * HE_NCH * D_OUT * 4);
    float* st_part  = (float*)take((size_t)VV * ST_NCH * D_OUT * 4);

    hipMemsetAsync((char*)d_ws + zero_beg, 0, zero_end - zero_beg, stream);

    // split hi/lo + row norms (one launch, F re-read eliminated)
    prep_kernel<<<NN + MM + 2 * D_OUT, 256, 0, stream>>>(F, E, W_he, W_st,
                                                         Fs, Es, Whes, Wsts, rnF, rnE);
    centers_kernel<<<VV, 256, 0, stream>>>(T, centers, maskcnt);
    mask_kernel<<<(VV * MM + 255) / 256, 256, 0, stream>>>(centers, S, mask, maskcnt);

    // all four GEMMs in one grouped launch (dbuf prefetch, balanced XCD map)
    gemm_grouped<<<NB_ALL, 256, 0, stream>>>(Fs, Es, Whes, Wsts,
                                             he_sim, st_sim, Xw_he, Xw_st,
                                             rnF, rnE);

    // top-5 + degree counts (one launch)
    topk_kernel<<<NN + VV * MM, 64, 0, stream>>>(he_sim, st_sim, mask,
                                                 he_idx, st_idx, he_cnt, st_cnt);
    // CSR offsets (both sides, one launch)
    scan_kernel<<<2, 1024, 0, stream>>>(he_cnt, he_off, st_cnt, st_off);
    // per-edge values + CSR fill (one launch)
    edge_kernel<<<NN + VV * MM, 256, 0, stream>>>(he_idx, st_idx, Xw_he, Xw_st,
                                                  he_cnt, st_cnt, he_off, st_off,
                                                  he_cur, st_cur, he_inv, st_inv,
                                                  he_ev, st_ev);
    // gather + gelu + partial pool (one launch)
    pool_gather_kernel<<<VV * HE_NCH + VV * ST_NCH, 256, 0, stream>>>(
        he_ev, st_ev, he_off, st_off, he_cnt, st_cnt, he_inv, st_inv,
        mask, he_part, st_part);
    // reduce + loss
    final_kernel<<<1, 256, 0, stream>>>(he_part, st_part, maskcnt, out);
}

// Round 7
// 235.966 us; speedup vs baseline: 4.8326x; 1.2839x over previous
//
#include <hip/hip_runtime.h>
#include <hip/hip_bf16.h>
#include <math.h>

// ---------------- problem constants ----------------
#define NN      8192
#define VV      8
#define PP      1024      // N / V
#define MM      2048
#define HE_DIM  1024
#define ST_DIM  512
#define D_OUT   256
#define K_HG    5
#define RADIUS  150.0f
#define TEMP    0.07f
#define EPSF    1e-12f

#define POOL_CHUNK 16
#define HE_NCH  (PP / POOL_CHUNK)   // 64
#define ST_NCH  (MM / POOL_CHUNK)   // 128

// grouped-GEMM block ranges
#define HE_TRI   36                 // 8x8 upper triangle
#define ST_TRI   136                // 16x16 upper triangle
#define NB_HE    (VV * HE_TRI)      // 288
#define NB_ST    ST_TRI             // 136
#define NB_PH    ((NN / 128) * (D_OUT / 128))   // 128
#define NB_PS    ((MM / 128) * (D_OUT / 128))   // 32
#define NB_ALL   (NB_HE + NB_ST + NB_PH + NB_PS) // 584 = 8 * 73

typedef __bf16 bf16x8 __attribute__((ext_vector_type(8)));
typedef float  f32x4  __attribute__((ext_vector_type(4)));
typedef unsigned short ushort_t;

typedef __attribute__((address_space(1))) void gvoid;
typedef __attribute__((address_space(3))) void svoid;
#define GLOAD16(g, l) __builtin_amdgcn_global_load_lds((gvoid*)(g), (svoid*)(l), 16, 0, 0)
#define FENCE() asm volatile("" ::: "memory")

// ---------------- fused: f32 -> (hi,lo) bf16 split + row L2 norm ----------------
__global__ __launch_bounds__(256) void prep_kernel(
    const float* __restrict__ F, const float* __restrict__ E,
    const float* __restrict__ Whe, const float* __restrict__ Wst,
    ushort_t* __restrict__ Fs, ushort_t* __restrict__ Es,
    ushort_t* __restrict__ Whes, ushort_t* __restrict__ Wsts,
    float* __restrict__ rnF, float* __restrict__ rnE)
{
    int b = blockIdx.x;
    const float* src; ushort_t* dst; float* rn; int K; long row;
    if (b < NN)                    { src = F;   dst = Fs;   rn = rnF;    K = HE_DIM; row = b; }
    else if (b < NN + MM)          { src = E;   dst = Es;   rn = rnE;    K = ST_DIM; row = b - NN; }
    else if (b < NN + MM + D_OUT)  { src = Whe; dst = Whes; rn = nullptr; K = HE_DIM; row = b - NN - MM; }
    else                           { src = Wst; dst = Wsts; rn = nullptr; K = ST_DIM; row = b - NN - MM - D_OUT; }
    const float4* srow = (const float4*)(src + row * (long)K);
    ushort_t* drow = dst + row * 2L * K;
    float s = 0.0f;
    for (int j4 = threadIdx.x; j4 < (K >> 2); j4 += 256) {
        float4 x = srow[j4];
        float xs[4] = {x.x, x.y, x.z, x.w};
        ushort_t hs[4], ls[4];
        #pragma unroll
        for (int t = 0; t < 4; ++t) {
            unsigned int bb = __float_as_uint(xs[t]);
            unsigned int hu = (bb + 0x7fffu + ((bb >> 16) & 1u)) >> 16;   // RNE bf16
            hs[t] = (ushort_t)hu;
            float hf = __uint_as_float(hu << 16);
            float l  = xs[t] - hf;                                        // exact
            unsigned int lb = __float_as_uint(l);
            ls[t] = (ushort_t)((lb + 0x7fffu + ((lb >> 16) & 1u)) >> 16);
            s += xs[t] * xs[t];
        }
        *(ushort4*)(drow + j4 * 4)     = make_ushort4(hs[0], hs[1], hs[2], hs[3]);
        *(ushort4*)(drow + K + j4 * 4) = make_ushort4(ls[0], ls[1], ls[2], ls[3]);
    }
    if (rn) {
        __shared__ float red[256];
        red[threadIdx.x] = s; __syncthreads();
        for (int o = 128; o > 0; o >>= 1) {
            if (threadIdx.x < o) red[threadIdx.x] += red[threadIdx.x + o];
            __syncthreads();
        }
        if (threadIdx.x == 0) rn[row] = 1.0f / fmaxf(sqrtf(red[0]), EPSF);
    }
}

// ---------------- merged region centroid + radius mask (one block per region) ----------------
__global__ __launch_bounds__(256) void centers_mask_kernel(
    const float* __restrict__ T, const float* __restrict__ S,
    int* __restrict__ mask, int* __restrict__ maskcnt)
{
    int v = blockIdx.x;
    float sx = 0.0f, sy = 0.0f;
    for (int i = threadIdx.x; i < PP; i += 256) {
        sx += T[(long)(v * PP + i) * 2 + 0];
        sy += T[(long)(v * PP + i) * 2 + 1];
    }
    __shared__ float rx[256], ry[256];
    __shared__ int   rc[256];
    rx[threadIdx.x] = sx; ry[threadIdx.x] = sy; __syncthreads();
    for (int o = 128; o > 0; o >>= 1) {
        if (threadIdx.x < o) { rx[threadIdx.x] += rx[threadIdx.x + o]; ry[threadIdx.x] += ry[threadIdx.x + o]; }
        __syncthreads();
    }
    float cx = rx[0] / (float)PP, cy = ry[0] / (float)PP;
    __syncthreads();
    int cnt = 0;
    for (int m = threadIdx.x; m < MM; m += 256) {
        float dx = cx - S[m * 2 + 0];
        float dy = cy - S[m * 2 + 1];
        int in = (sqrtf(dx * dx + dy * dy) < RADIUS) ? 1 : 0;
        mask[v * MM + m] = in;
        cnt += in;
    }
    rc[threadIdx.x] = cnt; __syncthreads();
    for (int o = 128; o > 0; o >>= 1) {
        if (threadIdx.x < o) rc[threadIdx.x] += rc[threadIdx.x + o];
        __syncthreads();
    }
    if (threadIdx.x == 0) maskcnt[v] = rc[0];
}

// ---------------- grouped split-bf16 MFMA GEMM ----------------
// 2-phase pipeline with COUNTED vmcnt (prefetch stays in flight across barrier)
// + XOR bank swizzle: LDS dest linear (global_load_lds), per-lane GLOBAL source
// pre-swizzled, ds_read applies the same XOR -> 8-way conflict becomes 2-way.
__global__ __launch_bounds__(256) void gemm_grouped(
    const ushort_t* __restrict__ Fs, const ushort_t* __restrict__ Es,
    const ushort_t* __restrict__ Whes, const ushort_t* __restrict__ Wsts,
    float* __restrict__ he_sim, float* __restrict__ st_sim,
    float* __restrict__ Xw_he, float* __restrict__ Xw_st,
    const float* __restrict__ rnF, const float* __restrict__ rnE)
{
    // Balanced XCD map: XCD k owns region k's 36 HE tiles (its Fs panel ~4MB = one L2)
    // plus a round-robin 37-slice of the ST/proj tiles.
    int bid = blockIdx.x;
    int xcd = bid & 7, j = bid >> 3;    // 584 = 8*73, bijective
    int id = (j < HE_TRI) ? (xcd * HE_TRI + j)
                          : (NB_HE + (j - HE_TRI) * 8 + xcd);

    const ushort_t *A, *B; float *C;
    const float *rA = nullptr, *rB = nullptr;
    int K, Nn, bm, bn, sym;
    if (id < NB_HE) {
        int z = id / HE_TRI, t = id - z * HE_TRI;
        int i = 0;
        while (t >= 8 - i) { t -= 8 - i; ++i; }
        bm = i * 128; bn = (i + t) * 128;
        A = B = Fs + (long)z * PP * 2 * HE_DIM;
        C = he_sim + (long)z * PP * PP;
        rA = rB = rnF + z * PP;
        K = HE_DIM; Nn = PP; sym = 1;
    } else if (id < NB_HE + NB_ST) {
        int t = id - NB_HE;
        int i = 0;
        while (t >= 16 - i) { t -= 16 - i; ++i; }
        bm = i * 128; bn = (i + t) * 128;
        A = B = Es; C = st_sim; rA = rB = rnE;
        K = ST_DIM; Nn = MM; sym = 1;
    } else if (id < NB_HE + NB_ST + NB_PH) {
        int t = id - (NB_HE + NB_ST);
        bm = (t >> 1) * 128; bn = (t & 1) * 128;
        A = Fs; B = Whes; C = Xw_he;
        K = HE_DIM; Nn = D_OUT; sym = 0;
    } else {
        int t = id - (NB_HE + NB_ST + NB_PH);
        bm = (t >> 1) * 128; bn = (t & 1) * 128;
        A = Es; B = Wsts; C = Xw_st;
        K = ST_DIM; Nn = D_OUT; sym = 0;
    }

    // 2 buffers x 4 tiles (AH, AL, BH, BL) x 8 KB = 64 KB
    __shared__ ushort_t sm[2][4][4096];
    const int tid  = threadIdx.x;
    const int lane = tid & 63, wave = tid >> 6;
    const int wr = wave >> 1, wc = wave & 1;
    const int fr = lane & 15, fg = lane >> 4;

    const long lda = 2L * K;
    // staging: lane writes LDS slot lane*16 (linear, HW-fixed). Source element
    // column pre-swizzled so that swizzled ds_read returns correct data.
    const int srow = wave * 16 + (lane >> 2);            // tile row (first half; +64 second)
    const int scol = (((lane & 3) ^ ((srow >> 1) & 3)) * 8);  // XOR-swizzled src col (elems)
    // ((row+64)>>1)&3 == (row>>1)&3, so both halves share scol.

    auto STAGE = [&](int kk, int b) {
        const ushort_t* ga = A + (long)(bm + srow) * lda + kk + scol;
        const ushort_t* gb = B + (long)(bn + srow) * lda + kk + scol;
        char* AH = (char*)&sm[b][0][0] + wave * 1024;
        char* AL = (char*)&sm[b][1][0] + wave * 1024;
        char* BH = (char*)&sm[b][2][0] + wave * 1024;
        char* BL = (char*)&sm[b][3][0] + wave * 1024;
        GLOAD16(ga,                AH); GLOAD16(ga + 64 * lda,     AH + 4096);
        GLOAD16(ga + K,            AL); GLOAD16(ga + K + 64 * lda, AL + 4096);
        GLOAD16(gb,                BH); GLOAD16(gb + 64 * lda,     BH + 4096);
        GLOAD16(gb + K,            BL); GLOAD16(gb + K + 64 * lda, BL + 4096);
    };

    f32x4 acc[4][4] = {};
    STAGE(0, 0);
    int buf = 0;
    for (int kk = 0; kk < K; kk += 32) {
        if (kk + 32 < K) {
            STAGE(kk + 32, buf ^ 1);                      // prefetch next (8 loads)
            asm volatile("s_waitcnt vmcnt(8)" ::: "memory");  // only current buf must land
        } else {
            asm volatile("s_waitcnt vmcnt(0)" ::: "memory");
        }
        FENCE(); __builtin_amdgcn_s_barrier(); FENCE();
        bf16x8 ah[4], al[4], bh[4], bl[4];
        #pragma unroll
        for (int m = 0; m < 4; ++m) {
            int row = wr * 64 + m * 16 + fr;
            int ro = row * 64 + ((fg ^ ((row >> 1) & 3)) * 16);   // byte offset, swizzled
            ah[m] = *(const bf16x8*)((const char*)&sm[buf][0][0] + ro);
            al[m] = *(const bf16x8*)((const char*)&sm[buf][1][0] + ro);
        }
        #pragma unroll
        for (int n = 0; n < 4; ++n) {
            int row = wc * 64 + n * 16 + fr;
            int ro = row * 64 + ((fg ^ ((row >> 1) & 3)) * 16);
            bh[n] = *(const bf16x8*)((const char*)&sm[buf][2][0] + ro);
            bl[n] = *(const bf16x8*)((const char*)&sm[buf][3][0] + ro);
        }
        #pragma unroll
        for (int m = 0; m < 4; ++m)
            #pragma unroll
            for (int n = 0; n < 4; ++n) {
                acc[m][n] = __builtin_amdgcn_mfma_f32_16x16x32_bf16(ah[m], bh[n], acc[m][n], 0, 0, 0);
                acc[m][n] = __builtin_amdgcn_mfma_f32_16x16x32_bf16(al[m], bh[n], acc[m][n], 0, 0, 0);
                acc[m][n] = __builtin_amdgcn_mfma_f32_16x16x32_bf16(ah[m], bl[n], acc[m][n], 0, 0, 0);
            }
        FENCE(); __builtin_amdgcn_s_barrier(); FENCE();   // all waves done reading buf
        buf ^= 1;
    }

    #pragma unroll
    for (int m = 0; m < 4; ++m) {
        #pragma unroll
        for (int r = 0; r < 4; ++r) {
            int row = bm + wr * 64 + m * 16 + fg * 4 + r;
            float ra = rA ? rA[row] : 1.0f;
            #pragma unroll
            for (int n = 0; n < 4; ++n) {
                int col = bn + wc * 64 + n * 16 + fr;
                float rb = rB ? rB[col] : 1.0f;
                float val = acc[m][n][r] * ra * rb;
                C[(long)row * Nn + col] = val;
                if (sym && bn > bm) C[(long)col * Nn + row] = val;
            }
        }
    }
}

// ---------------- merged top-5 per row + degree counts ----------------
__global__ __launch_bounds__(64) void topk_kernel(
    const float* __restrict__ he_sim, const float* __restrict__ st_sim,
    const int* __restrict__ mask,
    int* __restrict__ he_idx, int* __restrict__ st_idx,
    int* __restrict__ he_cnt, int* __restrict__ st_cnt)
{
    int gb = blockIdx.x;
    const float* row; const int* mk = nullptr; int* outIdx; int* cntp; int n;
    if (gb < NN) {
        int z = gb >> 10, e = gb & (PP - 1);
        row = he_sim + (long)z * PP * PP + (long)e * PP;
        outIdx = he_idx + (long)gb * K_HG;
        cntp = he_cnt + z * PP;
        n = PP;
    } else {
        int g2 = gb - NN;
        int z = g2 >> 11, e = g2 & (MM - 1);
        mk = mask + (long)z * MM;
        row = st_sim + (long)e * MM;
        outIdx = st_idx + (long)g2 * K_HG;
        cntp = st_cnt + z * MM;
        n = MM;
        if (mk[e] == 0) {
            if (threadIdx.x == 0) {
                #pragma unroll
                for (int r = 0; r < K_HG; ++r) outIdx[r] = -1;
            }
            return;
        }
    }
    int lane = threadIdx.x;
    float v[K_HG]; int ix[K_HG];
    #pragma unroll
    for (int r = 0; r < K_HG; ++r) { v[r] = -INFINITY; ix[r] = 0x7fffffff; }
    for (int jj = lane; jj < n; jj += 64) {
        if (mk && mk[jj] == 0) continue;
        float s = row[jj];
        if (s > v[K_HG - 1]) {
            int p = K_HG - 1;
            #pragma unroll
            for (int q = K_HG - 1; q >= 1; --q) {
                if (s > v[q - 1]) { v[q] = v[q - 1]; ix[q] = ix[q - 1]; p = q - 1; }
                else break;
            }
            v[p] = s; ix[p] = jj;
        }
    }
    int sel[K_HG];
    #pragma unroll
    for (int r = 0; r < K_HG; ++r) {
        float bv = v[0]; int bi = ix[0];
        for (int o = 32; o > 0; o >>= 1) {
            float ov = __shfl_xor(bv, o, 64);
            int   oi = __shfl_xor(bi, o, 64);
            if (ov > bv || (ov == bv && oi < bi)) { bv = ov; bi = oi; }
        }
        if (lane == 0) { outIdx[r] = bi; sel[r] = bi; }
        if (v[0] == bv && ix[0] == bi) {
            #pragma unroll
            for (int p = 0; p < K_HG - 1; ++p) { v[p] = v[p + 1]; ix[p] = ix[p + 1]; }
            v[K_HG - 1] = -INFINITY; ix[K_HG - 1] = 0x7fffffff;
        }
    }
    if (lane == 0) {
        #pragma unroll
        for (int r = 0; r < K_HG; ++r) atomicAdd(&cntp[sel[r]], 1);
    }
}

// ---------------- merged exclusive prefix scans (2 blocks) ----------------
template <int ELT>
__device__ void scan_impl(const int* __restrict__ cnt, int* __restrict__ off) {
    int tid = threadIdx.x;
    int base = tid * ELT;
    int loc[ELT]; int s = 0;
    #pragma unroll
    for (int i = 0; i < ELT; ++i) { loc[i] = s; s += cnt[base + i]; }
    __shared__ int red[1024];
    red[tid] = s; __syncthreads();
    for (int o = 1; o < 1024; o <<= 1) {
        int t = (tid >= o) ? red[tid - o] : 0;
        __syncthreads();
        red[tid] += t;
        __syncthreads();
    }
    int pre = red[tid] - s;
    #pragma unroll
    for (int i = 0; i < ELT; ++i) off[base + i] = pre + loc[i];
}

__global__ __launch_bounds__(1024) void scan_kernel(
    const int* __restrict__ he_cnt, int* __restrict__ he_off,
    const int* __restrict__ st_cnt, int* __restrict__ st_off) {
    if (blockIdx.x == 0) scan_impl<NN / 1024>(he_cnt, he_off);
    else                 scan_impl<(VV * MM) / 1024>(st_cnt, st_off);
}

// ---------------- merged per-edge value + CSR fill ----------------
__global__ __launch_bounds__(256) void edge_kernel(
    const int* __restrict__ he_idx, const int* __restrict__ st_idx,
    const float* __restrict__ Xw_he, const float* __restrict__ Xw_st,
    const int* __restrict__ he_cnt, const int* __restrict__ st_cnt,
    const int* __restrict__ he_off, const int* __restrict__ st_off,
    int* __restrict__ he_cur, int* __restrict__ st_cur,
    int* __restrict__ he_inv, int* __restrict__ st_inv,
    float* __restrict__ he_ev, float* __restrict__ st_ev)
{
    int b = blockIdx.x;
    const int *idx, *cnt, *off; const float* Xw;
    int *cur, *inv; float* ev;
    int ge, gbase, rowsPerZ; long xwBase;
    if (b < NN) {
        ge = b; int z = ge >> 10;
        idx = he_idx; Xw = Xw_he; cnt = he_cnt; off = he_off;
        cur = he_cur; inv = he_inv; ev = he_ev;
        rowsPerZ = PP; gbase = z * PP; xwBase = (long)z * PP;
    } else {
        ge = b - NN; int z = ge >> 11;
        idx = st_idx; Xw = Xw_st; cnt = st_cnt; off = st_off;
        cur = st_cur; inv = st_inv; ev = st_ev;
        rowsPerZ = MM; gbase = z * MM; xwBase = 0;
    }
    int mm[K_HG];
    #pragma unroll
    for (int k = 0; k < K_HG; ++k) mm[k] = idx[(long)ge * K_HG + k];
    if (mm[0] < 0) return;   // masked-out ST edge
    int d = threadIdx.x;
    float val = 0.0f;
    #pragma unroll
    for (int k = 0; k < K_HG; ++k) {
        int m = mm[k];
        if (m < 0 || m >= rowsPerZ) continue;
        float w = rsqrtf(fmaxf((float)cnt[gbase + m], EPSF));
        val += w * Xw[(xwBase + m) * D_OUT + d];
    }
    ev[(long)ge * D_OUT + d] = val * (1.0f / (float)K_HG);
    if (d < K_HG) {
        int m = mm[d];
        if (m >= 0 && m < rowsPerZ) {
            int g = gbase + m;
            int pos = atomicAdd(&cur[g], 1);
            inv[off[g] + pos] = ge;
        }
    }
}

// ---------------- node gather + Dv^-1/2 + GELU + partial pool ----------------
__global__ __launch_bounds__(256) void pool_gather_kernel(
    const float* __restrict__ he_ev, const float* __restrict__ st_ev,
    const int* __restrict__ he_off, const int* __restrict__ st_off,
    const int* __restrict__ he_cnt, const int* __restrict__ st_cnt,
    const int* __restrict__ he_inv, const int* __restrict__ st_inv,
    const int* __restrict__ mask,
    float* __restrict__ he_part, float* __restrict__ st_part)
{
    int blk = blockIdx.x;
    const float* ev; const int *off, *cnt, *inv, *msk = nullptr;
    float* partial; int gbase, i0;
    if (blk < VV * HE_NCH) {
        int z = blk >> 6, c = blk & (HE_NCH - 1);
        ev = he_ev; off = he_off; cnt = he_cnt; inv = he_inv;
        partial = he_part + (long)blk * D_OUT;
        gbase = z * PP; i0 = c * POOL_CHUNK;
    } else {
        int b2 = blk - VV * HE_NCH;
        int z = b2 >> 7, c = b2 & (ST_NCH - 1);
        ev = st_ev; off = st_off; cnt = st_cnt; inv = st_inv;
        msk = mask;
        partial = st_part + (long)b2 * D_OUT;
        gbase = z * MM; i0 = c * POOL_CHUNK;
    }
    int d = threadIdx.x;
    float s = 0.0f;
    for (int i = 0; i < POOL_CHUNK; ++i) {
        int g = gbase + i0 + i;
        if (msk && msk[g] == 0) continue;
        int cn = cnt[g], c0 = off[g];
        float a = 0.0f;
        for (int e = 0; e < cn; ++e)
            a += ev[(long)inv[c0 + e] * D_OUT + d];
        float w = rsqrtf(fmaxf((float)cn, EPSF));
        float x = w * a;
        s += 0.5f * x * (1.0f + erff(x * 0.70710678118654752f));   // exact GELU
    }
    partial[d] = s;
}

// ---------------- parallel partial reduce -> z vectors ----------------
__global__ __launch_bounds__(256) void pool_reduce_kernel(
    const float* __restrict__ he_part, const float* __restrict__ st_part,
    const int* __restrict__ maskcnt,
    float* __restrict__ z_he, float* __restrict__ z_st)
{
    int b = blockIdx.x, d = threadIdx.x;
    if (b < VV) {
        float s = 0.0f;
        for (int c = 0; c < HE_NCH; ++c) s += he_part[(long)(b * HE_NCH + c) * D_OUT + d];
        z_he[b * D_OUT + d] = s / (float)PP;
    } else {
        int v = b - VV;
        float s = 0.0f;
        for (int c = 0; c < ST_NCH; ++c) s += st_part[(long)(v * ST_NCH + c) * D_OUT + d];
        z_st[v * D_OUT + d] = s / (float)maskcnt[v];
    }
}

// ---------------- final contrastive loss (tiny) ----------------
__global__ __launch_bounds__(64) void final_kernel(const float* __restrict__ zhe,
                                                   const float* __restrict__ zst,
                                                   float* __restrict__ out) {
    __shared__ float he[VV][D_OUT];
    __shared__ float st[VV][D_OUT];
    __shared__ float lg[VV][VV];
    __shared__ float rn_he[VV], rn_st[VV];
    int t = threadIdx.x;
    for (int i = t; i < VV * D_OUT; i += 64) {
        he[i >> 8][i & 255] = zhe[i];
        st[i >> 8][i & 255] = zst[i];
    }
    __syncthreads();
    if (t < VV) {
        float s = 0.0f;
        for (int d2 = 0; d2 < D_OUT; ++d2) s += he[t][d2] * he[t][d2];
        rn_he[t] = 1.0f / fmaxf(sqrtf(s), EPSF);
    } else if (t < 2 * VV) {
        int v = t - VV; float s = 0.0f;
        for (int d2 = 0; d2 < D_OUT; ++d2) s += st[v][d2] * st[v][d2];
        rn_st[v] = 1.0f / fmaxf(sqrtf(s), EPSF);
    }
    __syncthreads();
    int v = t >> 3, w2 = t & 7;
    float dot = 0.0f;
    for (int d2 = 0; d2 < D_OUT; ++d2) dot += he[v][d2] * st[w2][d2];
    lg[v][w2] = dot * rn_he[v] * rn_st[w2] / TEMP;
    __syncthreads();
    if (t == 0) {
        float l1 = 0.0f, l2 = 0.0f;
        for (int i = 0; i < VV; ++i) {
            float mx = -1e30f;
            for (int jj = 0; jj < VV; ++jj) mx = fmaxf(mx, lg[i][jj]);
            float se = 0.0f;
            for (int jj = 0; jj < VV; ++jj) se += expf(lg[i][jj] - mx);
            l1 += lg[i][i] - (mx + logf(se));
            float mx2 = -1e30f;
            for (int jj = 0; jj < VV; ++jj) mx2 = fmaxf(mx2, lg[jj][i]);
            float se2 = 0.0f;
            for (int jj = 0; jj < VV; ++jj) se2 += expf(lg[jj][i] - mx2);
            l2 += lg[i][i] - (mx2 + logf(se2));
        }
        out[0] = 0.5f * (-(l1 / (float)VV) - (l2 / (float)VV));
    }
}

// ---------------- launch ----------------
extern "C" void kernel_launch(void* const* d_in, const int* in_sizes, int n_in,
                              void* d_out, int out_size, void* d_ws, size_t ws_size,
                              hipStream_t stream) {
    const float* F    = (const float*)d_in[0];
    const float* T    = (const float*)d_in[1];
    const float* E    = (const float*)d_in[3];
    const float* S    = (const float*)d_in[4];
    const float* W_he = (const float*)d_in[5];
    const float* W_st = (const float*)d_in[6];
    float* out = (float*)d_out;

    size_t off = 0;
    auto take = [&](size_t bytes) -> void* {
        void* p = (char*)d_ws + off;
        off += (bytes + 255) & ~(size_t)255;
        return p;
    };
    ushort_t* Fs    = (ushort_t*)take((size_t)NN * 2 * HE_DIM * 2);   // 33.5 MB
    ushort_t* Es    = (ushort_t*)take((size_t)MM * 2 * ST_DIM * 2);   // 4.2 MB
    ushort_t* Whes  = (ushort_t*)take((size_t)D_OUT * 2 * HE_DIM * 2);
    ushort_t* Wsts  = (ushort_t*)take((size_t)D_OUT * 2 * ST_DIM * 2);
    float* Xw_he    = (float*)take((size_t)NN * D_OUT * 4);           // 8 MB
    float* Xw_st    = (float*)take((size_t)MM * D_OUT * 4);           // 2 MB
    float* rnF      = (float*)take((size_t)NN * 4);
    float* rnE      = (float*)take((size_t)MM * 4);
    int*   mask     = (int*)  take((size_t)VV * MM * 4);
    int*   maskcnt  = (int*)  take((size_t)VV * 4);
    float* he_sim   = (float*)take((size_t)VV * PP * PP * 4);         // 32 MB
    float* st_sim   = (float*)take((size_t)MM * MM * 4);              // 16 MB
    int*   he_idx   = (int*)  take((size_t)NN * K_HG * 4);
    int*   st_idx   = (int*)  take((size_t)VV * MM * K_HG * 4);
    // zero-init region (one memset): counts + cursors
    size_t zero_beg = off;
    int*   he_cnt   = (int*)  take((size_t)NN * 4);
    int*   st_cnt   = (int*)  take((size_t)VV * MM * 4);
    int*   he_cur   = (int*)  take((size_t)NN * 4);
    int*   st_cur   = (int*)  take((size_t)VV * MM * 4);
    size_t zero_end = off;
    int*   he_off   = (int*)  take((size_t)NN * 4);
    int*   st_off   = (int*)  take((size_t)VV * MM * 4);
    int*   he_inv   = (int*)  take((size_t)NN * K_HG * 4);
    int*   st_inv   = (int*)  take((size_t)VV * MM * K_HG * 4);
    float* he_ev    = (float*)take((size_t)NN * D_OUT * 4);           // 8 MB
    float* st_ev    = (float*)take((size_t)VV * MM * D_OUT * 4);      // 16 MB
    float* he_part  = (float*)take((size_t)VV * HE_NCH * D_OUT * 4);
    float* st_part  = (float*)take((size_t)VV * ST_NCH * D_OUT * 4);
    float* z_he     = (float*)take((size_t)VV * D_OUT * 4);
    float* z_st     = (float*)take((size_t)VV * D_OUT * 4);

    hipMemsetAsync((char*)d_ws + zero_beg, 0, zero_end - zero_beg, stream);

    // split hi/lo + row norms (one launch)
    prep_kernel<<<NN + MM + 2 * D_OUT, 256, 0, stream>>>(F, E, W_he, W_st,
                                                         Fs, Es, Whes, Wsts, rnF, rnE);
    // centroid + radius mask per region (merged, no atomics)
    centers_mask_kernel<<<VV, 256, 0, stream>>>(T, S, mask, maskcnt);

    // all four GEMMs in one grouped launch (counted-vmcnt pipeline + swizzle)
    gemm_grouped<<<NB_ALL, 256, 0, stream>>>(Fs, Es, Whes, Wsts,
                                             he_sim, st_sim, Xw_he, Xw_st,
                                             rnF, rnE);

    // top-5 + degree counts (one launch)
    topk_kernel<<<NN + VV * MM, 64, 0, stream>>>(he_sim, st_sim, mask,
                                                 he_idx, st_idx, he_cnt, st_cnt);
    // CSR offsets (both sides, one launch)
    scan_kernel<<<2, 1024, 0, stream>>>(he_cnt, he_off, st_cnt, st_off);
    // per-edge values + CSR fill (one launch)
    edge_kernel<<<NN + VV * MM, 256, 0, stream>>>(he_idx, st_idx, Xw_he, Xw_st,
                                                  he_cnt, st_cnt, he_off, st_off,
                                                  he_cur, st_cur, he_inv, st_inv,
                                                  he_ev, st_ev);
    // gather + gelu + partial pool (one launch)
    pool_gather_kernel<<<VV * HE_NCH + VV * ST_NCH, 256, 0, stream>>>(
        he_ev, st_ev, he_off, st_off, he_cnt, st_cnt, he_inv, st_inv,
        mask, he_part, st_part);
    // parallel partial reduce, then tiny loss
    pool_reduce_kernel<<<2 * VV, 256, 0, stream>>>(he_part, st_part, maskcnt, z_he, z_st);
    final_kernel<<<1, 64, 0, stream>>>(z_he, z_st, out);
}